// Round 3
// baseline (287.497 us; speedup 1.0000x reference)
//
#include <hip/hip_runtime.h>

typedef float f32x4 __attribute__((ext_vector_type(4)));
typedef short short8 __attribute__((ext_vector_type(8)));
typedef short short4v __attribute__((ext_vector_type(4)));
typedef unsigned short ushort_t;

#define D_MODEL 1024
#define N_HEAD 16
#define SEQ 2048
#define BATCH 2
#define M_TOK 4096  // B*S
#define HD 1024     // N_HEAD*D_K
// (1/sqrt(64)) * log2(e), folded into Q-GEMM epilogue; attention uses exp2
#define QSCALE_L2E 0.1803368801111f

__device__ __forceinline__ ushort_t f2bf(float f) {
    union { float f; unsigned int u; } x; x.f = f;
    unsigned int r = x.u + 0x7fffu + ((x.u >> 16) & 1u);
    return (ushort_t)(r >> 16);
}
// round-to-nearest without tie fix (values > 0): fewer VALU ops
__device__ __forceinline__ ushort_t f2bf_fast(float f) {
    union { float f; unsigned int u; } x; x.f = f;
    return (ushort_t)((x.u + 0x8000u) >> 16);
}

__device__ __forceinline__ void async_copy16(const ushort_t* gptr, ushort_t* lptr) {
    __builtin_amdgcn_global_load_lds(
        (const __attribute__((address_space(1))) unsigned int*)gptr,
        (__attribute__((address_space(3))) unsigned int*)lptr, 16, 0, 0);
}

// ---------------- 4 weight transposes fp32 [1024][1024] -> bf16 [C][R], batched ----------------
__global__ __launch_bounds__(256) void transpose_cast4(const float* __restrict__ w0,
                                                       const float* __restrict__ w1,
                                                       const float* __restrict__ w2,
                                                       const float* __restrict__ w3,
                                                       ushort_t* __restrict__ o0,
                                                       ushort_t* __restrict__ o1,
                                                       ushort_t* __restrict__ o2,
                                                       ushort_t* __restrict__ o3) {
    const int R = D_MODEL, C = D_MODEL;
    int z = blockIdx.z;
    const float* in = (z == 0) ? w0 : (z == 1) ? w1 : (z == 2) ? w2 : w3;
    ushort_t* out = (z == 0) ? o0 : (z == 1) ? o1 : (z == 2) ? o2 : o3;
    __shared__ ushort_t t[32][33];
    int bc = blockIdx.x * 32, br = blockIdx.y * 32;
    for (int i = threadIdx.y; i < 32; i += 8)
        t[i][threadIdx.x] = f2bf(in[(size_t)(br + i) * C + bc + threadIdx.x]);
    __syncthreads();
    for (int i = threadIdx.y; i < 32; i += 8)
        out[(size_t)(bc + i) * R + br + threadIdx.x] = t[threadIdx.x][i];
}

// ---------------- cast fp32 -> bf16, 3 tensors batched over grid.z ----------------
__global__ __launch_bounds__(256) void cast_bf16_3(const float* __restrict__ q,
                                                   const float* __restrict__ k,
                                                   const float* __restrict__ v,
                                                   ushort_t* __restrict__ qo,
                                                   ushort_t* __restrict__ ko,
                                                   ushort_t* __restrict__ vo) {
    int z = blockIdx.z;
    const float* s = (z == 0) ? q : (z == 1) ? k : v;
    ushort_t* d = (z == 0) ? qo : (z == 1) ? ko : vo;
    size_t i = ((size_t)blockIdx.x * 256 + threadIdx.x) * 8;
    float4 a = *(const float4*)(s + i);
    float4 b = *(const float4*)(s + i + 4);
    ushort_t tmp[8] = {f2bf(a.x), f2bf(a.y), f2bf(a.z), f2bf(a.w),
                       f2bf(b.x), f2bf(b.y), f2bf(b.z), f2bf(b.w)};
    *(short8*)(d + i) = *(short8*)tmp;
}

// ---------------- QKV projection: 128x128 tile, both operands async, grid.z batched ----------------
// z==0: Q, scaled by QSCALE_L2E.  z==1: K.  z==2: V, written TRANSPOSED (Vt[n][m]).
__global__ __launch_bounds__(256) void gemm_qkv(const ushort_t* __restrict__ qb,
                                                const ushort_t* __restrict__ kb,
                                                const ushort_t* __restrict__ vb,
                                                const ushort_t* __restrict__ wq,
                                                const ushort_t* __restrict__ wk,
                                                const ushort_t* __restrict__ wv,
                                                ushort_t* __restrict__ Qo,
                                                ushort_t* __restrict__ Ko,
                                                ushort_t* __restrict__ VtO) {
    __shared__ ushort_t As[128 * 32];
    __shared__ ushort_t Bs[128 * 32];
    const int z = blockIdx.z;
    const ushort_t* A = (z == 0) ? qb : (z == 1) ? kb : vb;
    const ushort_t* Bt = (z == 0) ? wq : (z == 1) ? wk : wv;
    const int tid = threadIdx.x;
    const int wave = tid >> 6, lane = tid & 63;
    const int quad = lane >> 4, l16 = lane & 15;
    const int m0 = blockIdx.y * 128, n0 = blockIdx.x * 128;
    const int wm = (wave >> 1) * 64, wn = (wave & 1) * 64;
    const int K = D_MODEL, N = D_MODEL;

    f32x4 acc[4][4];
    for (int i = 0; i < 4; ++i)
        for (int j = 0; j < 4; ++j) acc[i][j] = (f32x4){0.f, 0.f, 0.f, 0.f};

    for (int kk = 0; kk < K; kk += 32) {
        __syncthreads();
        #pragma unroll
        for (int c = 0; c < 2; ++c) {
            int flat = ((wave * 2 + c) * 64 + lane) * 8;
            int r = flat >> 5, col = flat & 31;
            async_copy16(Bt + (size_t)(n0 + r) * K + kk + col, &Bs[(wave * 2 + c) * 512]);
            async_copy16(A + (size_t)(m0 + r) * K + kk + col, &As[(wave * 2 + c) * 512]);
        }
        __syncthreads();
        short8 af[4], bfr[4];
        #pragma unroll
        for (int i = 0; i < 4; ++i)
            af[i] = *(const short8*)&As[(wm + i * 16 + l16) * 32 + quad * 8];
        #pragma unroll
        for (int j = 0; j < 4; ++j)
            bfr[j] = *(const short8*)&Bs[(wn + j * 16 + l16) * 32 + quad * 8];
        #pragma unroll
        for (int i = 0; i < 4; ++i)
            #pragma unroll
            for (int j = 0; j < 4; ++j)
                acc[i][j] = __builtin_amdgcn_mfma_f32_16x16x32_bf16(af[i], bfr[j], acc[i][j], 0, 0, 0);
    }
    if (z == 2) {
        // V^T: Vt[n][m]; the 4 r-values are contiguous in m -> packed 8B stores
        #pragma unroll
        for (int i = 0; i < 4; ++i)
            #pragma unroll
            for (int j = 0; j < 4; ++j) {
                int n = n0 + wn + j * 16 + l16;
                int m = m0 + wm + i * 16 + quad * 4;
                ushort_t tmp[4];
                #pragma unroll
                for (int r = 0; r < 4; ++r) tmp[r] = f2bf(acc[i][j][r]);
                *(short4v*)&VtO[(size_t)n * M_TOK + m] = *(short4v*)tmp;
            }
    } else {
        ushort_t* C = (z == 0) ? Qo : Ko;
        const float scale = (z == 0) ? QSCALE_L2E : 1.0f;
        #pragma unroll
        for (int i = 0; i < 4; ++i)
            #pragma unroll
            for (int j = 0; j < 4; ++j) {
                int n = n0 + wn + j * 16 + l16;
                #pragma unroll
                for (int r = 0; r < 4; ++r) {
                    int m = m0 + wm + i * 16 + quad * 4 + r;
                    C[(size_t)m * N + n] = f2bf(acc[i][j][r] * scale);
                }
            }
    }
}

// ---------------- FC projection with fused bias + residual, fp32 out ----------------
__global__ __launch_bounds__(256) void gemm_fc(const ushort_t* __restrict__ A,
                                               const ushort_t* __restrict__ Bt,
                                               float* __restrict__ Cf,
                                               const float* __restrict__ bias,
                                               const float* __restrict__ resid) {
    __shared__ ushort_t As[128 * 32];
    __shared__ ushort_t Bs[128 * 32];
    const int tid = threadIdx.x;
    const int wave = tid >> 6, lane = tid & 63;
    const int quad = lane >> 4, l16 = lane & 15;
    const int m0 = blockIdx.y * 128, n0 = blockIdx.x * 128;
    const int wm = (wave >> 1) * 64, wn = (wave & 1) * 64;
    const int K = D_MODEL, N = D_MODEL;

    f32x4 acc[4][4];
    for (int i = 0; i < 4; ++i)
        for (int j = 0; j < 4; ++j) acc[i][j] = (f32x4){0.f, 0.f, 0.f, 0.f};

    for (int kk = 0; kk < K; kk += 32) {
        __syncthreads();
        #pragma unroll
        for (int c = 0; c < 2; ++c) {
            int flat = ((wave * 2 + c) * 64 + lane) * 8;
            int r = flat >> 5, col = flat & 31;
            async_copy16(Bt + (size_t)(n0 + r) * K + kk + col, &Bs[(wave * 2 + c) * 512]);
            async_copy16(A + (size_t)(m0 + r) * K + kk + col, &As[(wave * 2 + c) * 512]);
        }
        __syncthreads();
        short8 af[4], bfr[4];
        #pragma unroll
        for (int i = 0; i < 4; ++i)
            af[i] = *(const short8*)&As[(wm + i * 16 + l16) * 32 + quad * 8];
        #pragma unroll
        for (int j = 0; j < 4; ++j)
            bfr[j] = *(const short8*)&Bs[(wn + j * 16 + l16) * 32 + quad * 8];
        #pragma unroll
        for (int i = 0; i < 4; ++i)
            #pragma unroll
            for (int j = 0; j < 4; ++j)
                acc[i][j] = __builtin_amdgcn_mfma_f32_16x16x32_bf16(af[i], bfr[j], acc[i][j], 0, 0, 0);
    }
    #pragma unroll
    for (int i = 0; i < 4; ++i)
        #pragma unroll
        for (int j = 0; j < 4; ++j) {
            int n = n0 + wn + j * 16 + l16;
            #pragma unroll
            for (int r = 0; r < 4; ++r) {
                int m = m0 + wm + i * 16 + quad * 4 + r;
                Cf[(size_t)m * N + n] = acc[i][j][r] + bias[n] + resid[(size_t)m * N + n];
            }
        }
}

// ---------------- flash attention, double-buffered K/V, one barrier per iter ----------------
// Qh pre-scaled by (1/8)*log2(e); exp via exp2. Vt globally transposed.
// Row sums accumulated via MFMA against a ones-fragment (no shuffles, no v_add chain).
__global__ __launch_bounds__(256) void attn64(const ushort_t* __restrict__ Qh,
                                              const ushort_t* __restrict__ Kh,
                                              const ushort_t* __restrict__ Vt,
                                              ushort_t* __restrict__ O) {
    __shared__ ushort_t Ks[2][64 * 64];   // [buf][d-half][k-row][32]
    __shared__ ushort_t Vs[2][64 * 64];   // [buf][k-half][d-row][32]
    __shared__ ushort_t Ps[4][16 * 72];   // per-wave P tile, stride 72
    const int tid = threadIdx.x;
    const int wave = tid >> 6, lane = tid & 63;
    const int quad = lane >> 4, l16 = lane & 15;
    const int b = blockIdx.z, h = blockIdx.y, qt = blockIdx.x;
    const size_t base = (size_t)b * SEQ * HD + h * 64;
    const ushort_t* Qb = Qh + base + (size_t)(qt * 64) * HD;
    const ushort_t* Kb = Kh + base;
    const ushort_t* Vb = Vt + (size_t)(h * 64) * M_TOK + (size_t)b * SEQ;

    short8 qf[2];
    {
        int qr = wave * 16 + l16;
        #pragma unroll
        for (int s = 0; s < 2; ++s)
            qf[s] = *(const short8*)(Qb + (size_t)qr * HD + s * 32 + quad * 8);
    }
    const short8 ones = {16256, 16256, 16256, 16256, 16256, 16256, 16256, 16256};  // bf16 1.0
    f32x4 oacc[4];
    f32x4 lacc = (f32x4){0.f, 0.f, 0.f, 0.f};
    #pragma unroll
    for (int vt = 0; vt < 4; ++vt) oacc[vt] = (f32x4){0.f, 0.f, 0.f, 0.f};

    ushort_t* Pw = Ps[wave];

    // stage K/V tile kt into buffer buf
    auto stage = [&](int kt, int buf) {
        #pragma unroll
        for (int c = 0; c < 2; ++c) {
            int g = wave * 2 + c;
            int sH = g >> 2, row = (g & 3) * 16 + (lane >> 2), e = (lane & 3) * 8;
            async_copy16(Kb + (size_t)(kt * 64 + row) * HD + sH * 32 + e, &Ks[buf][g * 512]);
            async_copy16(Vb + (size_t)row * M_TOK + kt * 64 + sH * 32 + e, &Vs[buf][g * 512]);
        }
    };

    stage(0, 0);
    for (int kt = 0; kt < SEQ / 64; ++kt) {
        const int buf = kt & 1;
        __syncthreads();  // drains outstanding global_load_lds for buf, releases buf^1
        if (kt + 1 < SEQ / 64) stage(kt + 1, buf ^ 1);  // overlaps entire compute phase

        f32x4 sacc[4];
        #pragma unroll
        for (int nt = 0; nt < 4; ++nt) sacc[nt] = (f32x4){0.f, 0.f, 0.f, 0.f};
        #pragma unroll
        for (int s = 0; s < 2; ++s)
            #pragma unroll
            for (int nt = 0; nt < 4; ++nt) {
                short8 kf = *(const short8*)&Ks[buf][s * 2048 + (nt * 16 + l16) * 32 + quad * 8];
                sacc[nt] = __builtin_amdgcn_mfma_f32_16x16x32_bf16(qf[s], kf, sacc[nt], 0, 0, 0);
            }

        #pragma unroll
        for (int nt = 0; nt < 4; ++nt)
            #pragma unroll
            for (int r = 0; r < 4; ++r) {
                float pv = exp2f(sacc[nt][r]);
                Pw[(quad * 4 + r) * 72 + nt * 16 + l16] = f2bf_fast(pv);
            }

        #pragma unroll
        for (int s = 0; s < 2; ++s) {
            short8 pf = *(const short8*)&Pw[l16 * 72 + s * 32 + quad * 8];
            lacc = __builtin_amdgcn_mfma_f32_16x16x32_bf16(pf, ones, lacc, 0, 0, 0);
            #pragma unroll
            for (int vt = 0; vt < 4; ++vt) {
                short8 vf = *(const short8*)&Vs[buf][s * 2048 + (vt * 16 + l16) * 32 + quad * 8];
                oacc[vt] = __builtin_amdgcn_mfma_f32_16x16x32_bf16(pf, vf, oacc[vt], 0, 0, 0);
            }
        }
    }

    ushort_t* Ob = O + base + (size_t)(qt * 64) * HD;
    #pragma unroll
    for (int r = 0; r < 4; ++r) {
        float inv = 1.f / lacc[r];
        int row = wave * 16 + quad * 4 + r;
        #pragma unroll
        for (int vt = 0; vt < 4; ++vt)
            Ob[(size_t)row * HD + vt * 16 + l16] = f2bf(oacc[vt][r] * inv);
    }
}

// ---------------- in-place LayerNorm, one block per row ----------------
__global__ __launch_bounds__(256) void ln_kernel(float* __restrict__ x,
                                                 const float* __restrict__ gamma,
                                                 const float* __restrict__ beta) {
    const int D = D_MODEL;
    float* xr = x + (size_t)blockIdx.x * D;
    const int tid = threadIdx.x;
    float4 v = *(const float4*)(xr + tid * 4);
    float s = v.x + v.y + v.z + v.w;
    float s2 = v.x * v.x + v.y * v.y + v.z * v.z + v.w * v.w;
    #pragma unroll
    for (int off = 1; off < 64; off <<= 1) {
        s += __shfl_xor(s, off, 64);
        s2 += __shfl_xor(s2, off, 64);
    }
    __shared__ float ws1[4], ws2[4];
    int wave = tid >> 6, lane = tid & 63;
    if (lane == 0) { ws1[wave] = s; ws2[wave] = s2; }
    __syncthreads();
    s = ws1[0] + ws1[1] + ws1[2] + ws1[3];
    s2 = ws2[0] + ws2[1] + ws2[2] + ws2[3];
    float mean = s * (1.f / D);
    float var = s2 * (1.f / D) - mean * mean;
    float rstd = rsqrtf(var + 1e-6f);
    float4 g = *(const float4*)(gamma + tid * 4);
    float4 bt = *(const float4*)(beta + tid * 4);
    float4 o;
    o.x = (v.x - mean) * rstd * g.x + bt.x;
    o.y = (v.y - mean) * rstd * g.y + bt.y;
    o.z = (v.z - mean) * rstd * g.z + bt.z;
    o.w = (v.w - mean) * rstd * g.w + bt.w;
    *(float4*)(xr + tid * 4) = o;
}

extern "C" void kernel_launch(void* const* d_in, const int* in_sizes, int n_in,
                              void* d_out, int out_size, void* d_ws, size_t ws_size,
                              hipStream_t stream) {
    const float* q = (const float*)d_in[0];
    const float* k = (const float*)d_in[1];
    const float* v = (const float*)d_in[2];
    const float* Wq = (const float*)d_in[3];
    const float* Wk = (const float*)d_in[4];
    const float* Wv = (const float*)d_in[5];
    const float* Wfc = (const float*)d_in[6];
    const float* bfc = (const float*)d_in[7];
    const float* gamma = (const float*)d_in[8];
    const float* beta = (const float*)d_in[9];
    float* out = (float*)d_out;

    char* ws = (char*)d_ws;
    const size_t MB = 1u << 20;
    ushort_t* WqT  = (ushort_t*)(ws + 0 * MB);
    ushort_t* WkT  = (ushort_t*)(ws + 2 * MB);
    ushort_t* WvT  = (ushort_t*)(ws + 4 * MB);
    ushort_t* WfcT = (ushort_t*)(ws + 6 * MB);
    ushort_t* qb   = (ushort_t*)(ws + 8 * MB);
    ushort_t* kb   = (ushort_t*)(ws + 16 * MB);
    ushort_t* vb   = (ushort_t*)(ws + 24 * MB);
    ushort_t* Qh   = (ushort_t*)(ws + 32 * MB);
    ushort_t* Kh   = (ushort_t*)(ws + 40 * MB);
    ushort_t* Vt   = (ushort_t*)(ws + 48 * MB);
    ushort_t* Oh   = (ushort_t*)(ws + 8 * MB);  // reuse qb slot after QKV GEMM

    const int M = M_TOK, D = D_MODEL;
    transpose_cast4<<<dim3(D / 32, D / 32, 4), dim3(32, 8), 0, stream>>>(
        Wq, Wk, Wv, Wfc, WqT, WkT, WvT, WfcT);

    cast_bf16_3<<<dim3(M * D / (256 * 8), 1, 3), 256, 0, stream>>>(q, k, v, qb, kb, vb);

    gemm_qkv<<<dim3(D / 128, M / 128, 3), 256, 0, stream>>>(qb, kb, vb, WqT, WkT, WvT, Qh, Kh, Vt);

    attn64<<<dim3(SEQ / 64, N_HEAD, BATCH), 256, 0, stream>>>(Qh, Kh, Vt, Oh);

    gemm_fc<<<dim3(D / 128, M / 128), 256, 0, stream>>>(Oh, WfcT, out, bfc, q);

    ln_kernel<<<M, 256, 0, stream>>>(out, gamma, beta);
}

// Round 4
// 271.891 us; speedup vs baseline: 1.0574x; 1.0574x over previous
//
#include <hip/hip_runtime.h>

typedef float f32x4 __attribute__((ext_vector_type(4)));
typedef short short8 __attribute__((ext_vector_type(8)));
typedef short short4v __attribute__((ext_vector_type(4)));
typedef unsigned short ushort_t;

#define D_MODEL 1024
#define N_HEAD 16
#define SEQ 2048
#define BATCH 2
#define M_TOK 4096  // B*S
#define HD 1024     // N_HEAD*D_K
// (1/sqrt(64)) * log2(e), folded into Q-GEMM epilogue; attention uses exp2
#define QSCALE_L2E 0.1803368801111f

__device__ __forceinline__ ushort_t f2bf(float f) {
    union { float f; unsigned int u; } x; x.f = f;
    unsigned int r = x.u + 0x7fffu + ((x.u >> 16) & 1u);
    return (ushort_t)(r >> 16);
}
// round-to-nearest without tie fix (values > 0): fewer VALU ops
__device__ __forceinline__ ushort_t f2bf_fast(float f) {
    union { float f; unsigned int u; } x; x.f = f;
    return (ushort_t)((x.u + 0x8000u) >> 16);
}

__device__ __forceinline__ void async_copy16(const ushort_t* gptr, ushort_t* lptr) {
    __builtin_amdgcn_global_load_lds(
        (const __attribute__((address_space(1))) unsigned int*)gptr,
        (__attribute__((address_space(3))) unsigned int*)lptr, 16, 0, 0);
}

// ---------------- 4 weight transposes fp32 [1024][1024] -> bf16 [C][R], batched ----------------
__global__ __launch_bounds__(256) void transpose_cast4(const float* __restrict__ w0,
                                                       const float* __restrict__ w1,
                                                       const float* __restrict__ w2,
                                                       const float* __restrict__ w3,
                                                       ushort_t* __restrict__ o0,
                                                       ushort_t* __restrict__ o1,
                                                       ushort_t* __restrict__ o2,
                                                       ushort_t* __restrict__ o3) {
    const int R = D_MODEL, C = D_MODEL;
    int z = blockIdx.z;
    const float* in = (z == 0) ? w0 : (z == 1) ? w1 : (z == 2) ? w2 : w3;
    ushort_t* out = (z == 0) ? o0 : (z == 1) ? o1 : (z == 2) ? o2 : o3;
    __shared__ ushort_t t[32][33];
    int bc = blockIdx.x * 32, br = blockIdx.y * 32;
    for (int i = threadIdx.y; i < 32; i += 8)
        t[i][threadIdx.x] = f2bf(in[(size_t)(br + i) * C + bc + threadIdx.x]);
    __syncthreads();
    for (int i = threadIdx.y; i < 32; i += 8)
        out[(size_t)(bc + i) * R + br + threadIdx.x] = t[threadIdx.x][i];
}

// ---------------- cast fp32 -> bf16, 3 tensors batched over grid.z ----------------
__global__ __launch_bounds__(256) void cast_bf16_3(const float* __restrict__ q,
                                                   const float* __restrict__ k,
                                                   const float* __restrict__ v,
                                                   ushort_t* __restrict__ qo,
                                                   ushort_t* __restrict__ ko,
                                                   ushort_t* __restrict__ vo) {
    int z = blockIdx.z;
    const float* s = (z == 0) ? q : (z == 1) ? k : v;
    ushort_t* d = (z == 0) ? qo : (z == 1) ? ko : vo;
    size_t i = ((size_t)blockIdx.x * 256 + threadIdx.x) * 8;
    float4 a = *(const float4*)(s + i);
    float4 b = *(const float4*)(s + i + 4);
    ushort_t tmp[8] = {f2bf(a.x), f2bf(a.y), f2bf(a.z), f2bf(a.w),
                       f2bf(b.x), f2bf(b.y), f2bf(b.z), f2bf(b.w)};
    *(short8*)(d + i) = *(short8*)tmp;
}

// ---------------- QKV projection: 128x128 tile, both operands async, grid.z batched ----------------
// z==0: Q, scaled by QSCALE_L2E.  z==1: K.  z==2: V, written TRANSPOSED (Vt[n][m]).
__global__ __launch_bounds__(256) void gemm_qkv(const ushort_t* __restrict__ qb,
                                                const ushort_t* __restrict__ kb,
                                                const ushort_t* __restrict__ vb,
                                                const ushort_t* __restrict__ wq,
                                                const ushort_t* __restrict__ wk,
                                                const ushort_t* __restrict__ wv,
                                                ushort_t* __restrict__ Qo,
                                                ushort_t* __restrict__ Ko,
                                                ushort_t* __restrict__ VtO) {
    __shared__ ushort_t As[128 * 32];
    __shared__ ushort_t Bs[128 * 32];
    const int z = blockIdx.z;
    const ushort_t* A = (z == 0) ? qb : (z == 1) ? kb : vb;
    const ushort_t* Bt = (z == 0) ? wq : (z == 1) ? wk : wv;
    const int tid = threadIdx.x;
    const int wave = tid >> 6, lane = tid & 63;
    const int quad = lane >> 4, l16 = lane & 15;
    const int m0 = blockIdx.y * 128, n0 = blockIdx.x * 128;
    const int wm = (wave >> 1) * 64, wn = (wave & 1) * 64;
    const int K = D_MODEL, N = D_MODEL;

    f32x4 acc[4][4];
    for (int i = 0; i < 4; ++i)
        for (int j = 0; j < 4; ++j) acc[i][j] = (f32x4){0.f, 0.f, 0.f, 0.f};

    for (int kk = 0; kk < K; kk += 32) {
        __syncthreads();
        #pragma unroll
        for (int c = 0; c < 2; ++c) {
            int flat = ((wave * 2 + c) * 64 + lane) * 8;
            int r = flat >> 5, col = flat & 31;
            async_copy16(Bt + (size_t)(n0 + r) * K + kk + col, &Bs[(wave * 2 + c) * 512]);
            async_copy16(A + (size_t)(m0 + r) * K + kk + col, &As[(wave * 2 + c) * 512]);
        }
        __syncthreads();
        short8 af[4], bfr[4];
        #pragma unroll
        for (int i = 0; i < 4; ++i)
            af[i] = *(const short8*)&As[(wm + i * 16 + l16) * 32 + quad * 8];
        #pragma unroll
        for (int j = 0; j < 4; ++j)
            bfr[j] = *(const short8*)&Bs[(wn + j * 16 + l16) * 32 + quad * 8];
        #pragma unroll
        for (int i = 0; i < 4; ++i)
            #pragma unroll
            for (int j = 0; j < 4; ++j)
                acc[i][j] = __builtin_amdgcn_mfma_f32_16x16x32_bf16(af[i], bfr[j], acc[i][j], 0, 0, 0);
    }
    if (z == 2) {
        // V^T: Vt[n][m]; the 4 r-values are contiguous in m -> packed 8B stores
        #pragma unroll
        for (int i = 0; i < 4; ++i)
            #pragma unroll
            for (int j = 0; j < 4; ++j) {
                int n = n0 + wn + j * 16 + l16;
                int m = m0 + wm + i * 16 + quad * 4;
                ushort_t tmp[4];
                #pragma unroll
                for (int r = 0; r < 4; ++r) tmp[r] = f2bf(acc[i][j][r]);
                *(short4v*)&VtO[(size_t)n * M_TOK + m] = *(short4v*)tmp;
            }
    } else {
        ushort_t* C = (z == 0) ? Qo : Ko;
        const float scale = (z == 0) ? QSCALE_L2E : 1.0f;
        #pragma unroll
        for (int i = 0; i < 4; ++i)
            #pragma unroll
            for (int j = 0; j < 4; ++j) {
                int n = n0 + wn + j * 16 + l16;
                #pragma unroll
                for (int r = 0; r < 4; ++r) {
                    int m = m0 + wm + i * 16 + quad * 4 + r;
                    C[(size_t)m * N + n] = f2bf(acc[i][j][r] * scale);
                }
            }
    }
}

// ---------------- FC projection with fused bias + residual, fp32 out ----------------
__global__ __launch_bounds__(256) void gemm_fc(const ushort_t* __restrict__ A,
                                               const ushort_t* __restrict__ Bt,
                                               float* __restrict__ Cf,
                                               const float* __restrict__ bias,
                                               const float* __restrict__ resid) {
    __shared__ ushort_t As[128 * 32];
    __shared__ ushort_t Bs[128 * 32];
    const int tid = threadIdx.x;
    const int wave = tid >> 6, lane = tid & 63;
    const int quad = lane >> 4, l16 = lane & 15;
    const int m0 = blockIdx.y * 128, n0 = blockIdx.x * 128;
    const int wm = (wave >> 1) * 64, wn = (wave & 1) * 64;
    const int K = D_MODEL, N = D_MODEL;

    f32x4 acc[4][4];
    for (int i = 0; i < 4; ++i)
        for (int j = 0; j < 4; ++j) acc[i][j] = (f32x4){0.f, 0.f, 0.f, 0.f};

    for (int kk = 0; kk < K; kk += 32) {
        __syncthreads();
        #pragma unroll
        for (int c = 0; c < 2; ++c) {
            int flat = ((wave * 2 + c) * 64 + lane) * 8;
            int r = flat >> 5, col = flat & 31;
            async_copy16(Bt + (size_t)(n0 + r) * K + kk + col, &Bs[(wave * 2 + c) * 512]);
            async_copy16(A + (size_t)(m0 + r) * K + kk + col, &As[(wave * 2 + c) * 512]);
        }
        __syncthreads();
        short8 af[4], bfr[4];
        #pragma unroll
        for (int i = 0; i < 4; ++i)
            af[i] = *(const short8*)&As[(wm + i * 16 + l16) * 32 + quad * 8];
        #pragma unroll
        for (int j = 0; j < 4; ++j)
            bfr[j] = *(const short8*)&Bs[(wn + j * 16 + l16) * 32 + quad * 8];
        #pragma unroll
        for (int i = 0; i < 4; ++i)
            #pragma unroll
            for (int j = 0; j < 4; ++j)
                acc[i][j] = __builtin_amdgcn_mfma_f32_16x16x32_bf16(af[i], bfr[j], acc[i][j], 0, 0, 0);
    }
    #pragma unroll
    for (int i = 0; i < 4; ++i)
        #pragma unroll
        for (int j = 0; j < 4; ++j) {
            int n = n0 + wn + j * 16 + l16;
            #pragma unroll
            for (int r = 0; r < 4; ++r) {
                int m = m0 + wm + i * 16 + quad * 4 + r;
                Cf[(size_t)m * N + n] = acc[i][j][r] + bias[n] + resid[(size_t)m * N + n];
            }
        }
}

// ---------------- flash attention, k-split + S^T trick ----------------
// Each wave owns a private 16-row k-slice per 64-k tile; Q (all 64 rows) lives in
// registers. QK^T computed as S^T = mfma(A=K, B=Q): its C-layout (k=quad*4+i,
// q=l16) IS the A-fragment layout of mfma_f32_16x16x16_bf16 -> P never touches
// LDS. K and V slices stage via double-buffered global_load_lds into wave-private
// LDS; no __syncthreads in the main loop. Cross-wave O/lsum reduction at the end.
__global__ __launch_bounds__(256, 3) void attn64(const ushort_t* __restrict__ Qh,
                                                 const ushort_t* __restrict__ Kh,
                                                 const ushort_t* __restrict__ Vt,
                                                 ushort_t* __restrict__ O) {
    // [0,8192): K  — per wave 2 bufs x [2 d-halves][16 rows][32 el]
    // [8192,16384): V — per wave 2 bufs x [64 d-rows][16 k-el]
    // epilogue overlay: two fp32 64x65 O-partial regions (33280 B)
    __shared__ ushort_t KVs[16768];
    __shared__ float lsb[4 * 64];
    const int tid = threadIdx.x;
    const int wave = tid >> 6, lane = tid & 63;
    const int quad = lane >> 4, l16 = lane & 15;
    const int b = blockIdx.z, h = blockIdx.y, qt = blockIdx.x;
    const size_t base = (size_t)b * SEQ * HD + h * 64;
    const ushort_t* Qb = Qh + base + (size_t)(qt * 64) * HD;
    const ushort_t* Kb = Kh + base;
    const ushort_t* Vb = Vt + (size_t)(h * 64) * M_TOK + (size_t)b * SEQ;

    ushort_t* Kw = KVs + wave * 2048;
    ushort_t* Vw = KVs + 8192 + wave * 2048;

    // Q fragments: all 64 q-rows (B-operand), resident for the whole loop
    short8 qf[4][2];
    #pragma unroll
    for (int nt = 0; nt < 4; ++nt)
        #pragma unroll
        for (int s = 0; s < 2; ++s)
            qf[nt][s] = *(const short8*)(Qb + (size_t)(nt * 16 + l16) * HD + s * 32 + quad * 8);

    f32x4 oacc[4][4];
    #pragma unroll
    for (int nt = 0; nt < 4; ++nt)
        #pragma unroll
        for (int dt = 0; dt < 4; ++dt) oacc[nt][dt] = (f32x4){0.f, 0.f, 0.f, 0.f};
    float lsum[4] = {0.f, 0.f, 0.f, 0.f};

    // DMA lane-invariant bases
    const ushort_t* Kg = Kb + (size_t)(wave * 16 + (lane >> 2)) * HD + (lane & 3) * 8;
    const ushort_t* Vg = Vb + (size_t)(lane >> 1) * M_TOK + wave * 16 + (lane & 1) * 8;
    ushort_t* KL = Kw + lane * 8;
    ushort_t* VL = Vw + lane * 8;

    // prologue: stage tile 0 into buf 0
    #pragma unroll
    for (int c = 0; c < 2; ++c) {
        async_copy16(Kg + c * 32, KL + c * 512);
        async_copy16(Vg + (size_t)c * 32 * M_TOK, VL + c * 512);
    }

    #pragma unroll 2
    for (int kt = 0; kt < SEQ / 64; ++kt) {
        const int buf = kt & 1;
        __builtin_amdgcn_s_waitcnt(0x0F70);  // vmcnt(0): this iter's DMAs have landed
        if (kt < SEQ / 64 - 1) {             // prefetch kt+1 into buf^1, overlaps compute
            #pragma unroll
            for (int c = 0; c < 2; ++c) {
                async_copy16(Kg + (size_t)(kt + 1) * 64 * HD + c * 32,
                             KL + (buf ^ 1) * 1024 + c * 512);
                async_copy16(Vg + (size_t)c * 32 * M_TOK + (kt + 1) * 64,
                             VL + (buf ^ 1) * 1024 + c * 512);
            }
        }
        // K fragments (A-operand): wave's 16 k-rows
        short8 kf[2];
        #pragma unroll
        for (int s = 0; s < 2; ++s)
            kf[s] = *(const short8*)&Kw[buf * 1024 + s * 512 + l16 * 32 + quad * 8];
        // V fragments (B-operand of 16x16x16): [d=dt*16+l16][k=quad*4+j]
        short4v vf[4];
        #pragma unroll
        for (int dt = 0; dt < 4; ++dt)
            vf[dt] = *(const short4v*)&Vw[buf * 1024 + (dt * 16 + l16) * 16 + quad * 4];

        // S^T = K·Q^T : lane holds S[q=nt*16+l16][k=slice + quad*4+i]
        f32x4 sacc[4];
        #pragma unroll
        for (int nt = 0; nt < 4; ++nt) sacc[nt] = (f32x4){0.f, 0.f, 0.f, 0.f};
        #pragma unroll
        for (int s = 0; s < 2; ++s)
            #pragma unroll
            for (int nt = 0; nt < 4; ++nt)
                sacc[nt] = __builtin_amdgcn_mfma_f32_16x16x32_bf16(kf[s], qf[nt][s], sacc[nt], 0, 0, 0);

        // exp2, pack straight into PV A-fragments (no LDS round-trip)
        short4v pf[4];
        #pragma unroll
        for (int nt = 0; nt < 4; ++nt) {
            ushort_t tmp[4];
            #pragma unroll
            for (int i = 0; i < 4; ++i) {
                float pv = exp2f(sacc[nt][i]);
                lsum[nt] += pv;
                tmp[i] = f2bf_fast(pv);
            }
            pf[nt] = *(short4v*)tmp;
        }
        // PV: O_partial[q][d] over this wave's k-slice
        #pragma unroll
        for (int nt = 0; nt < 4; ++nt)
            #pragma unroll
            for (int dt = 0; dt < 4; ++dt)
                oacc[nt][dt] = __builtin_amdgcn_mfma_f32_16x16x16bf16_1k(pf[nt], vf[dt], oacc[nt][dt], 0, 0, 0);
    }

    // lsum: sum over this wave's k-quads, publish per-wave partial
    #pragma unroll
    for (int nt = 0; nt < 4; ++nt) {
        lsum[nt] += __shfl_xor(lsum[nt], 16, 64);
        lsum[nt] += __shfl_xor(lsum[nt], 32, 64);
    }
    if (quad == 0) {
        #pragma unroll
        for (int nt = 0; nt < 4; ++nt) lsb[wave * 64 + nt * 16 + l16] = lsum[nt];
    }
    __syncthreads();  // loop LDS use done; repurpose KVs as fp32 O-partial regions

    float* R0 = (float*)KVs;
    float* R1 = R0 + 64 * 65;
    {
        float* R = (wave & 1) ? R1 : R0;
        if (wave < 2) {
            #pragma unroll
            for (int nt = 0; nt < 4; ++nt)
                #pragma unroll
                for (int dt = 0; dt < 4; ++dt)
                    #pragma unroll
                    for (int i = 0; i < 4; ++i)
                        R[(nt * 16 + quad * 4 + i) * 65 + dt * 16 + l16] = oacc[nt][dt][i];
        }
        __syncthreads();
        if (wave >= 2) {
            #pragma unroll
            for (int nt = 0; nt < 4; ++nt)
                #pragma unroll
                for (int dt = 0; dt < 4; ++dt)
                    #pragma unroll
                    for (int i = 0; i < 4; ++i)
                        R[(nt * 16 + quad * 4 + i) * 65 + dt * 16 + l16] += oacc[nt][dt][i];
        }
        __syncthreads();
    }
    // final: wave w owns q-rows [w*16, w*16+16)
    float inv[4];
    #pragma unroll
    for (int i = 0; i < 4; ++i) {
        int qrow = wave * 16 + quad * 4 + i;
        float t = lsb[qrow] + lsb[64 + qrow] + lsb[128 + qrow] + lsb[192 + qrow];
        inv[i] = 1.f / t;
    }
    ushort_t* Ob = O + base + (size_t)(qt * 64) * HD;
    #pragma unroll
    for (int i = 0; i < 4; ++i) {
        int qrow = wave * 16 + quad * 4 + i;
        #pragma unroll
        for (int dt = 0; dt < 4; ++dt) {
            int d = dt * 16 + l16;
            float val = R0[qrow * 65 + d] + R1[qrow * 65 + d];
            Ob[(size_t)qrow * HD + d] = f2bf(val * inv[i]);
        }
    }
}

// ---------------- in-place LayerNorm, one block per row ----------------
__global__ __launch_bounds__(256) void ln_kernel(float* __restrict__ x,
                                                 const float* __restrict__ gamma,
                                                 const float* __restrict__ beta) {
    const int D = D_MODEL;
    float* xr = x + (size_t)blockIdx.x * D;
    const int tid = threadIdx.x;
    float4 v = *(const float4*)(xr + tid * 4);
    float s = v.x + v.y + v.z + v.w;
    float s2 = v.x * v.x + v.y * v.y + v.z * v.z + v.w * v.w;
    #pragma unroll
    for (int off = 1; off < 64; off <<= 1) {
        s += __shfl_xor(s, off, 64);
        s2 += __shfl_xor(s2, off, 64);
    }
    __shared__ float ws1[4], ws2[4];
    int wave = tid >> 6, lane = tid & 63;
    if (lane == 0) { ws1[wave] = s; ws2[wave] = s2; }
    __syncthreads();
    s = ws1[0] + ws1[1] + ws1[2] + ws1[3];
    s2 = ws2[0] + ws2[1] + ws2[2] + ws2[3];
    float mean = s * (1.f / D);
    float var = s2 * (1.f / D) - mean * mean;
    float rstd = rsqrtf(var + 1e-6f);
    float4 g = *(const float4*)(gamma + tid * 4);
    float4 bt = *(const float4*)(beta + tid * 4);
    float4 o;
    o.x = (v.x - mean) * rstd * g.x + bt.x;
    o.y = (v.y - mean) * rstd * g.y + bt.y;
    o.z = (v.z - mean) * rstd * g.z + bt.z;
    o.w = (v.w - mean) * rstd * g.w + bt.w;
    *(float4*)(xr + tid * 4) = o;
}

extern "C" void kernel_launch(void* const* d_in, const int* in_sizes, int n_in,
                              void* d_out, int out_size, void* d_ws, size_t ws_size,
                              hipStream_t stream) {
    const float* q = (const float*)d_in[0];
    const float* k = (const float*)d_in[1];
    const float* v = (const float*)d_in[2];
    const float* Wq = (const float*)d_in[3];
    const float* Wk = (const float*)d_in[4];
    const float* Wv = (const float*)d_in[5];
    const float* Wfc = (const float*)d_in[6];
    const float* bfc = (const float*)d_in[7];
    const float* gamma = (const float*)d_in[8];
    const float* beta = (const float*)d_in[9];
    float* out = (float*)d_out;

    char* ws = (char*)d_ws;
    const size_t MB = 1u << 20;
    ushort_t* WqT  = (ushort_t*)(ws + 0 * MB);
    ushort_t* WkT  = (ushort_t*)(ws + 2 * MB);
    ushort_t* WvT  = (ushort_t*)(ws + 4 * MB);
    ushort_t* WfcT = (ushort_t*)(ws + 6 * MB);
    ushort_t* qb   = (ushort_t*)(ws + 8 * MB);
    ushort_t* kb   = (ushort_t*)(ws + 16 * MB);
    ushort_t* vb   = (ushort_t*)(ws + 24 * MB);
    ushort_t* Qh   = (ushort_t*)(ws + 32 * MB);
    ushort_t* Kh   = (ushort_t*)(ws + 40 * MB);
    ushort_t* Vt   = (ushort_t*)(ws + 48 * MB);
    ushort_t* Oh   = (ushort_t*)(ws + 8 * MB);  // reuse qb slot after QKV GEMM

    const int M = M_TOK, D = D_MODEL;
    transpose_cast4<<<dim3(D / 32, D / 32, 4), dim3(32, 8), 0, stream>>>(
        Wq, Wk, Wv, Wfc, WqT, WkT, WvT, WfcT);

    cast_bf16_3<<<dim3(M * D / (256 * 8), 1, 3), 256, 0, stream>>>(q, k, v, qb, kb, vb);

    gemm_qkv<<<dim3(D / 128, M / 128, 3), 256, 0, stream>>>(qb, kb, vb, WqT, WkT, WvT, Qh, Kh, Vt);

    attn64<<<dim3(SEQ / 64, N_HEAD, BATCH), 256, 0, stream>>>(Qh, Kh, Vt, Oh);

    gemm_fc<<<dim3(D / 128, M / 128), 256, 0, stream>>>(Oh, WfcT, out, bfc, q);

    ln_kernel<<<M, 256, 0, stream>>>(out, gamma, beta);
}

// Round 5
// 258.029 us; speedup vs baseline: 1.1142x; 1.0537x over previous
//
#include <hip/hip_runtime.h>

typedef float f32x4 __attribute__((ext_vector_type(4)));
typedef short short8 __attribute__((ext_vector_type(8)));
typedef short short4v __attribute__((ext_vector_type(4)));
typedef unsigned short ushort_t;

#define D_MODEL 1024
#define N_HEAD 16
#define SEQ 2048
#define BATCH 2
#define M_TOK 4096  // B*S
#define HD 1024     // N_HEAD*D_K
#define NT 32       // SEQ/64 k-tiles
// (1/sqrt(64)) * log2(e), folded into Q-GEMM epilogue; attention uses exp2
#define QSCALE_L2E 0.1803368801111f

__device__ __forceinline__ ushort_t f2bf(float f) {
    union { float f; unsigned int u; } x; x.f = f;
    unsigned int r = x.u + 0x7fffu + ((x.u >> 16) & 1u);
    return (ushort_t)(r >> 16);
}
// round-to-nearest without tie fix (values > 0): fewer VALU ops
__device__ __forceinline__ ushort_t f2bf_fast(float f) {
    union { float f; unsigned int u; } x; x.f = f;
    return (ushort_t)((x.u + 0x8000u) >> 16);
}

__device__ __forceinline__ void async_copy16(const ushort_t* gptr, ushort_t* lptr) {
    __builtin_amdgcn_global_load_lds(
        (const __attribute__((address_space(1))) unsigned int*)gptr,
        (__attribute__((address_space(3))) unsigned int*)lptr, 16, 0, 0);
}

// ---------------- 4 weight transposes fp32 [1024][1024] -> bf16 [C][R], batched ----------------
__global__ __launch_bounds__(256) void transpose_cast4(const float* __restrict__ w0,
                                                       const float* __restrict__ w1,
                                                       const float* __restrict__ w2,
                                                       const float* __restrict__ w3,
                                                       ushort_t* __restrict__ o0,
                                                       ushort_t* __restrict__ o1,
                                                       ushort_t* __restrict__ o2,
                                                       ushort_t* __restrict__ o3) {
    const int R = D_MODEL, C = D_MODEL;
    int z = blockIdx.z;
    const float* in = (z == 0) ? w0 : (z == 1) ? w1 : (z == 2) ? w2 : w3;
    ushort_t* out = (z == 0) ? o0 : (z == 1) ? o1 : (z == 2) ? o2 : o3;
    __shared__ ushort_t t[32][33];
    int bc = blockIdx.x * 32, br = blockIdx.y * 32;
    for (int i = threadIdx.y; i < 32; i += 8)
        t[i][threadIdx.x] = f2bf(in[(size_t)(br + i) * C + bc + threadIdx.x]);
    __syncthreads();
    for (int i = threadIdx.y; i < 32; i += 8)
        out[(size_t)(bc + i) * R + br + threadIdx.x] = t[threadIdx.x][i];
}

// ---------------- cast fp32 -> bf16, 3 tensors batched over grid.z ----------------
__global__ __launch_bounds__(256) void cast_bf16_3(const float* __restrict__ q,
                                                   const float* __restrict__ k,
                                                   const float* __restrict__ v,
                                                   ushort_t* __restrict__ qo,
                                                   ushort_t* __restrict__ ko,
                                                   ushort_t* __restrict__ vo) {
    int z = blockIdx.z;
    const float* s = (z == 0) ? q : (z == 1) ? k : v;
    ushort_t* d = (z == 0) ? qo : (z == 1) ? ko : vo;
    size_t i = ((size_t)blockIdx.x * 256 + threadIdx.x) * 8;
    float4 a = *(const float4*)(s + i);
    float4 b = *(const float4*)(s + i + 4);
    ushort_t tmp[8] = {f2bf(a.x), f2bf(a.y), f2bf(a.z), f2bf(a.w),
                       f2bf(b.x), f2bf(b.y), f2bf(b.z), f2bf(b.w)};
    *(short8*)(d + i) = *(short8*)tmp;
}

// ---------------- QKV projection: 128x128 tile, both operands async, grid.z batched ----------------
// z==0: Q, scaled by QSCALE_L2E.  z==1: K.  z==2: V, written TRANSPOSED (Vt[n][m])
// with each 16-token group rotated by ((n>>2)&3)*4 so attn's LDS reads are bank-conflict-free.
__global__ __launch_bounds__(256) void gemm_qkv(const ushort_t* __restrict__ qb,
                                                const ushort_t* __restrict__ kb,
                                                const ushort_t* __restrict__ vb,
                                                const ushort_t* __restrict__ wq,
                                                const ushort_t* __restrict__ wk,
                                                const ushort_t* __restrict__ wv,
                                                ushort_t* __restrict__ Qo,
                                                ushort_t* __restrict__ Ko,
                                                ushort_t* __restrict__ VtO) {
    __shared__ ushort_t As[128 * 32];
    __shared__ ushort_t Bs[128 * 32];
    const int z = blockIdx.z;
    const ushort_t* A = (z == 0) ? qb : (z == 1) ? kb : vb;
    const ushort_t* Bt = (z == 0) ? wq : (z == 1) ? wk : wv;
    const int tid = threadIdx.x;
    const int wave = tid >> 6, lane = tid & 63;
    const int quad = lane >> 4, l16 = lane & 15;
    const int m0 = blockIdx.y * 128, n0 = blockIdx.x * 128;
    const int wm = (wave >> 1) * 64, wn = (wave & 1) * 64;
    const int K = D_MODEL, N = D_MODEL;

    f32x4 acc[4][4];
    for (int i = 0; i < 4; ++i)
        for (int j = 0; j < 4; ++j) acc[i][j] = (f32x4){0.f, 0.f, 0.f, 0.f};

    for (int kk = 0; kk < K; kk += 32) {
        __syncthreads();
        #pragma unroll
        for (int c = 0; c < 2; ++c) {
            int flat = ((wave * 2 + c) * 64 + lane) * 8;
            int r = flat >> 5, col = flat & 31;
            async_copy16(Bt + (size_t)(n0 + r) * K + kk + col, &Bs[(wave * 2 + c) * 512]);
            async_copy16(A + (size_t)(m0 + r) * K + kk + col, &As[(wave * 2 + c) * 512]);
        }
        __syncthreads();
        short8 af[4], bfr[4];
        #pragma unroll
        for (int i = 0; i < 4; ++i)
            af[i] = *(const short8*)&As[(wm + i * 16 + l16) * 32 + quad * 8];
        #pragma unroll
        for (int j = 0; j < 4; ++j)
            bfr[j] = *(const short8*)&Bs[(wn + j * 16 + l16) * 32 + quad * 8];
        #pragma unroll
        for (int i = 0; i < 4; ++i)
            #pragma unroll
            for (int j = 0; j < 4; ++j)
                acc[i][j] = __builtin_amdgcn_mfma_f32_16x16x32_bf16(af[i], bfr[j], acc[i][j], 0, 0, 0);
    }
    if (z == 2) {
        // V^T with k-rotation: within each 16-token block, quad -> (quad + (n>>2)) & 3
        #pragma unroll
        for (int i = 0; i < 4; ++i)
            #pragma unroll
            for (int j = 0; j < 4; ++j) {
                int n = n0 + wn + j * 16 + l16;
                int mBase = m0 + wm + i * 16;
                int quadR = (quad + (n >> 2)) & 3;
                ushort_t tmp[4];
                #pragma unroll
                for (int r = 0; r < 4; ++r) tmp[r] = f2bf(acc[i][j][r]);
                *(short4v*)&VtO[(size_t)n * M_TOK + mBase + quadR * 4] = *(short4v*)tmp;
            }
    } else {
        ushort_t* C = (z == 0) ? Qo : Ko;
        const float scale = (z == 0) ? QSCALE_L2E : 1.0f;
        #pragma unroll
        for (int i = 0; i < 4; ++i)
            #pragma unroll
            for (int j = 0; j < 4; ++j) {
                int n = n0 + wn + j * 16 + l16;
                #pragma unroll
                for (int r = 0; r < 4; ++r) {
                    int m = m0 + wm + i * 16 + quad * 4 + r;
                    C[(size_t)m * N + n] = f2bf(acc[i][j][r] * scale);
                }
            }
    }
}

// ---------------- FC projection, 128x64 tiles (2 blocks/CU), fused bias+residual ----------------
__global__ __launch_bounds__(256) void gemm_fc(const ushort_t* __restrict__ A,
                                               const ushort_t* __restrict__ Bt,
                                               float* __restrict__ Cf,
                                               const float* __restrict__ bias,
                                               const float* __restrict__ resid) {
    __shared__ ushort_t As[128 * 32];
    __shared__ ushort_t Bs[64 * 32];
    const int tid = threadIdx.x;
    const int wave = tid >> 6, lane = tid & 63;
    const int quad = lane >> 4, l16 = lane & 15;
    const int m0 = blockIdx.y * 128, n0 = blockIdx.x * 64;
    const int K = D_MODEL, N = D_MODEL;

    f32x4 acc[2][4];
    for (int i = 0; i < 2; ++i)
        for (int j = 0; j < 4; ++j) acc[i][j] = (f32x4){0.f, 0.f, 0.f, 0.f};

    for (int kk = 0; kk < K; kk += 32) {
        __syncthreads();
        #pragma unroll
        for (int c = 0; c < 2; ++c) {  // A: 8 chunks, wave handles 2
            int g = wave * 2 + c;
            int flat = (g * 64 + lane) * 8;
            int r = flat >> 5, col = flat & 31;
            async_copy16(A + (size_t)(m0 + r) * K + kk + col, &As[g * 512]);
        }
        {  // B: 4 chunks, wave handles 1
            int flat = (wave * 64 + lane) * 8;
            int r = flat >> 5, col = flat & 31;
            async_copy16(Bt + (size_t)(n0 + r) * K + kk + col, &Bs[wave * 512]);
        }
        __syncthreads();
        short8 af[2], bfr[4];
        #pragma unroll
        for (int i = 0; i < 2; ++i)
            af[i] = *(const short8*)&As[(wave * 32 + i * 16 + l16) * 32 + quad * 8];
        #pragma unroll
        for (int j = 0; j < 4; ++j)
            bfr[j] = *(const short8*)&Bs[(j * 16 + l16) * 32 + quad * 8];
        #pragma unroll
        for (int i = 0; i < 2; ++i)
            #pragma unroll
            for (int j = 0; j < 4; ++j)
                acc[i][j] = __builtin_amdgcn_mfma_f32_16x16x32_bf16(af[i], bfr[j], acc[i][j], 0, 0, 0);
    }
    #pragma unroll
    for (int i = 0; i < 2; ++i)
        #pragma unroll
        for (int j = 0; j < 4; ++j) {
            int n = n0 + j * 16 + l16;
            #pragma unroll
            for (int r = 0; r < 4; ++r) {
                int m = m0 + wave * 32 + i * 16 + quad * 4 + r;
                Cf[(size_t)m * N + n] = acc[i][j][r] + bias[n] + resid[(size_t)m * N + n];
            }
        }
}

// ---------------- flash attention: k-split, K direct-from-global, V dist-2 DMA ----------------
// Each wave owns a 16-row k-slice per 64-k tile. Q (64 rows) + K-frags in registers.
// S^T = mfma(A=K, B=Q): C-layout == PV A-layout -> P stays in registers.
// V staged wave-private via global_load_lds, 3 rotating buffers (prefetch distance 2),
// manual s_waitcnt vmcnt(2) (vmcnt(0) only on the last iter). No barriers in the loop.
__global__ __launch_bounds__(256, 3) void attn64(const ushort_t* __restrict__ Qh,
                                                 const ushort_t* __restrict__ Kh,
                                                 const ushort_t* __restrict__ Vt,
                                                 ushort_t* __restrict__ O) {
    // loop phase: V buffers 4 waves x 3 bufs x 2KB = 24576 B at offset 0
    // epilogue overlay: two fp32 64x65 regions (33280 B) at offset 0; lsb at 33280
    __shared__ __align__(16) char smem[34304];
    const int tid = threadIdx.x;
    const int wave = tid >> 6, lane = tid & 63;
    const int quad = lane >> 4, l16 = lane & 15;
    const int b = blockIdx.z, h = blockIdx.y, qt = blockIdx.x;
    const size_t base = (size_t)b * SEQ * HD + h * 64;
    const ushort_t* Qb = Qh + base + (size_t)(qt * 64) * HD;
    const ushort_t* Kb = Kh + base;
    const ushort_t* Vb = Vt + (size_t)(h * 64) * M_TOK + (size_t)b * SEQ;

    ushort_t* Vw = (ushort_t*)smem + wave * 3072;
    float* lsb = (float*)(smem + 33280);

    // Q fragments: all 64 q-rows (B-operand), resident for the whole loop
    short8 qf[4][2];
    #pragma unroll
    for (int nt = 0; nt < 4; ++nt)
        #pragma unroll
        for (int s = 0; s < 2; ++s)
            qf[nt][s] = *(const short8*)(Qb + (size_t)(nt * 16 + l16) * HD + s * 32 + quad * 8);

    f32x4 oacc[4][4];
    #pragma unroll
    for (int nt = 0; nt < 4; ++nt)
        #pragma unroll
        for (int dt = 0; dt < 4; ++dt) oacc[nt][dt] = (f32x4){0.f, 0.f, 0.f, 0.f};
    float lsum[4] = {0.f, 0.f, 0.f, 0.f};

    // K fragment source (direct global): row = kt*64 + wave*16 + l16, col s*32 + quad*8
    const ushort_t* Kr = Kb + (size_t)(wave * 16 + l16) * HD + quad * 8;
    // V DMA source/dest
    const ushort_t* Vg = Vb + (size_t)(lane >> 1) * M_TOK + wave * 16 + (lane & 1) * 8;
    ushort_t* VLd = Vw + lane * 8;

    // prologue: kf(0) regular loads, then V(0), V(1) DMAs (order matters for vmcnt)
    short8 kf0[2], kf1[2];
    #pragma unroll
    for (int s = 0; s < 2; ++s) kf0[s] = *(const short8*)(Kr + s * 32);
    #pragma unroll
    for (int c = 0; c < 2; ++c)
        async_copy16(Vg + (size_t)c * 32 * M_TOK, VLd + c * 512);
    #pragma unroll
    for (int c = 0; c < 2; ++c)
        async_copy16(Vg + (size_t)c * 32 * M_TOK + 64, VLd + 1024 + c * 512);

    ushort_t *vb0 = Vw, *vb1 = Vw + 1024, *vb2 = Vw + 2048;
    const int rot = (l16 >> 2) & 3;  // V k-rotation (matches gemm_qkv epilogue)

    for (int kt = 0; kt < NT; ++kt) {
        if (kt == NT - 1) __builtin_amdgcn_s_waitcnt(0x0F70);  // vmcnt(0)
        else              __builtin_amdgcn_s_waitcnt(0x0F72);  // vmcnt(2)

        // prefetch K(kt+1) frags (regular loads, compiler-tracked)
        if (kt + 1 < NT) {
            #pragma unroll
            for (int s = 0; s < 2; ++s)
                kf1[s] = *(const short8*)(Kr + (size_t)(kt + 1) * 64 * HD + s * 32);
        }
        // prefetch V(kt+2) into vb2 (distance 2)
        if (kt + 2 < NT) {
            #pragma unroll
            for (int c = 0; c < 2; ++c)
                async_copy16(Vg + (size_t)c * 32 * M_TOK + (kt + 2) * 64, vb2 + lane * 8 + c * 512);
        }

        // V fragments (B-operand of 16x16x16): [d=dt*16+l16][k=quad*4+j], rotated
        short4v vf[4];
        #pragma unroll
        for (int dt = 0; dt < 4; ++dt)
            vf[dt] = *(const short4v*)&vb0[(dt * 16 + l16) * 16 + (((quad + rot) & 3) * 4)];

        // S^T = K·Q^T : lane holds S[q=nt*16+l16][k=slice + quad*4+i]
        f32x4 sacc[4];
        #pragma unroll
        for (int nt = 0; nt < 4; ++nt) sacc[nt] = (f32x4){0.f, 0.f, 0.f, 0.f};
        #pragma unroll
        for (int s = 0; s < 2; ++s)
            #pragma unroll
            for (int nt = 0; nt < 4; ++nt)
                sacc[nt] = __builtin_amdgcn_mfma_f32_16x16x32_bf16(kf0[s], qf[nt][s], sacc[nt], 0, 0, 0);

        // exp2 (single v_exp_f32), pack straight into PV A-fragments
        short4v pf[4];
        #pragma unroll
        for (int nt = 0; nt < 4; ++nt) {
            ushort_t tmp[4];
            #pragma unroll
            for (int i = 0; i < 4; ++i) {
                float pv = __builtin_amdgcn_exp2f(sacc[nt][i]);
                lsum[nt] += pv;
                tmp[i] = f2bf_fast(pv);
            }
            pf[nt] = *(short4v*)tmp;
        }
        // PV over this wave's k-slice
        #pragma unroll
        for (int nt = 0; nt < 4; ++nt)
            #pragma unroll
            for (int dt = 0; dt < 4; ++dt)
                oacc[nt][dt] = __builtin_amdgcn_mfma_f32_16x16x16bf16_1k(pf[nt], vf[dt], oacc[nt][dt], 0, 0, 0);

        kf0[0] = kf1[0]; kf0[1] = kf1[1];
        ushort_t* t = vb0; vb0 = vb1; vb1 = vb2; vb2 = t;
    }

    // lsum: sum over this wave's k-quads, publish per-wave partial
    #pragma unroll
    for (int nt = 0; nt < 4; ++nt) {
        lsum[nt] += __shfl_xor(lsum[nt], 16, 64);
        lsum[nt] += __shfl_xor(lsum[nt], 32, 64);
    }
    if (quad == 0) {
        #pragma unroll
        for (int nt = 0; nt < 4; ++nt) lsb[wave * 64 + nt * 16 + l16] = lsum[nt];
    }
    __syncthreads();  // loop LDS use done; repurpose smem as fp32 O-partial regions

    float* R0 = (float*)smem;
    float* R1 = R0 + 64 * 65;
    {
        float* R = (wave & 1) ? R1 : R0;
        if (wave < 2) {
            #pragma unroll
            for (int nt = 0; nt < 4; ++nt)
                #pragma unroll
                for (int dt = 0; dt < 4; ++dt)
                    #pragma unroll
                    for (int i = 0; i < 4; ++i)
                        R[(nt * 16 + quad * 4 + i) * 65 + dt * 16 + l16] = oacc[nt][dt][i];
        }
        __syncthreads();
        if (wave >= 2) {
            #pragma unroll
            for (int nt = 0; nt < 4; ++nt)
                #pragma unroll
                for (int dt = 0; dt < 4; ++dt)
                    #pragma unroll
                    for (int i = 0; i < 4; ++i)
                        R[(nt * 16 + quad * 4 + i) * 65 + dt * 16 + l16] += oacc[nt][dt][i];
        }
        __syncthreads();
    }
    // final: wave w owns q-rows [w*16, w*16+16)
    float inv[4];
    #pragma unroll
    for (int i = 0; i < 4; ++i) {
        int qrow = wave * 16 + quad * 4 + i;
        float t = lsb[qrow] + lsb[64 + qrow] + lsb[128 + qrow] + lsb[192 + qrow];
        inv[i] = 1.f / t;
    }
    ushort_t* Ob = O + base + (size_t)(qt * 64) * HD;
    #pragma unroll
    for (int i = 0; i < 4; ++i) {
        int qrow = wave * 16 + quad * 4 + i;
        #pragma unroll
        for (int dt = 0; dt < 4; ++dt) {
            int d = dt * 16 + l16;
            float val = R0[qrow * 65 + d] + R1[qrow * 65 + d];
            Ob[(size_t)qrow * HD + d] = f2bf(val * inv[i]);
        }
    }
}

// ---------------- in-place LayerNorm, one block per row ----------------
__global__ __launch_bounds__(256) void ln_kernel(float* __restrict__ x,
                                                 const float* __restrict__ gamma,
                                                 const float* __restrict__ beta) {
    const int D = D_MODEL;
    float* xr = x + (size_t)blockIdx.x * D;
    const int tid = threadIdx.x;
    float4 v = *(const float4*)(xr + tid * 4);
    float s = v.x + v.y + v.z + v.w;
    float s2 = v.x * v.x + v.y * v.y + v.z * v.z + v.w * v.w;
    #pragma unroll
    for (int off = 1; off < 64; off <<= 1) {
        s += __shfl_xor(s, off, 64);
        s2 += __shfl_xor(s2, off, 64);
    }
    __shared__ float ws1[4], ws2[4];
    int wave = tid >> 6, lane = tid & 63;
    if (lane == 0) { ws1[wave] = s; ws2[wave] = s2; }
    __syncthreads();
    s = ws1[0] + ws1[1] + ws1[2] + ws1[3];
    s2 = ws2[0] + ws2[1] + ws2[2] + ws2[3];
    float mean = s * (1.f / D);
    float var = s2 * (1.f / D) - mean * mean;
    float rstd = rsqrtf(var + 1e-6f);
    float4 g = *(const float4*)(gamma + tid * 4);
    float4 bt = *(const float4*)(beta + tid * 4);
    float4 o;
    o.x = (v.x - mean) * rstd * g.x + bt.x;
    o.y = (v.y - mean) * rstd * g.y + bt.y;
    o.z = (v.z - mean) * rstd * g.z + bt.z;
    o.w = (v.w - mean) * rstd * g.w + bt.w;
    *(float4*)(xr + tid * 4) = o;
}

extern "C" void kernel_launch(void* const* d_in, const int* in_sizes, int n_in,
                              void* d_out, int out_size, void* d_ws, size_t ws_size,
                              hipStream_t stream) {
    const float* q = (const float*)d_in[0];
    const float* k = (const float*)d_in[1];
    const float* v = (const float*)d_in[2];
    const float* Wq = (const float*)d_in[3];
    const float* Wk = (const float*)d_in[4];
    const float* Wv = (const float*)d_in[5];
    const float* Wfc = (const float*)d_in[6];
    const float* bfc = (const float*)d_in[7];
    const float* gamma = (const float*)d_in[8];
    const float* beta = (const float*)d_in[9];
    float* out = (float*)d_out;

    char* ws = (char*)d_ws;
    const size_t MB = 1u << 20;
    ushort_t* WqT  = (ushort_t*)(ws + 0 * MB);
    ushort_t* WkT  = (ushort_t*)(ws + 2 * MB);
    ushort_t* WvT  = (ushort_t*)(ws + 4 * MB);
    ushort_t* WfcT = (ushort_t*)(ws + 6 * MB);
    ushort_t* qb   = (ushort_t*)(ws + 8 * MB);
    ushort_t* kb   = (ushort_t*)(ws + 16 * MB);
    ushort_t* vb   = (ushort_t*)(ws + 24 * MB);
    ushort_t* Qh   = (ushort_t*)(ws + 32 * MB);
    ushort_t* Kh   = (ushort_t*)(ws + 40 * MB);
    ushort_t* Vt   = (ushort_t*)(ws + 48 * MB);
    ushort_t* Oh   = (ushort_t*)(ws + 8 * MB);  // reuse qb slot after QKV GEMM

    const int M = M_TOK, D = D_MODEL;
    transpose_cast4<<<dim3(D / 32, D / 32, 4), dim3(32, 8), 0, stream>>>(
        Wq, Wk, Wv, Wfc, WqT, WkT, WvT, WfcT);

    cast_bf16_3<<<dim3(M * D / (256 * 8), 1, 3), 256, 0, stream>>>(q, k, v, qb, kb, vb);

    gemm_qkv<<<dim3(D / 128, M / 128, 3), 256, 0, stream>>>(qb, kb, vb, WqT, WkT, WvT, Qh, Kh, Vt);

    attn64<<<dim3(SEQ / 64, N_HEAD, BATCH), 256, 0, stream>>>(Qh, Kh, Vt, Oh);

    gemm_fc<<<dim3(D / 64, M / 128), 256, 0, stream>>>(Oh, WfcT, out, bfc, q);

    ln_kernel<<<M, 256, 0, stream>>>(out, gamma, beta);
}

// Round 6
// 254.091 us; speedup vs baseline: 1.1315x; 1.0155x over previous
//
#include <hip/hip_runtime.h>

typedef float f32x4 __attribute__((ext_vector_type(4)));
typedef short short8 __attribute__((ext_vector_type(8)));
typedef short short4v __attribute__((ext_vector_type(4)));
typedef unsigned short ushort_t;

#define D_MODEL 1024
#define N_HEAD 16
#define SEQ 2048
#define BATCH 2
#define M_TOK 4096  // B*S
#define HD 1024     // N_HEAD*D_K
#define NT 32       // SEQ/64 k-tiles
// (1/sqrt(64)) * log2(e), folded into Q-GEMM epilogue; attention uses exp2
#define QSCALE_L2E 0.1803368801111f

__device__ __forceinline__ ushort_t f2bf(float f) {
    union { float f; unsigned int u; } x; x.f = f;
    unsigned int r = x.u + 0x7fffu + ((x.u >> 16) & 1u);
    return (ushort_t)(r >> 16);
}
// round-to-nearest without tie fix (values > 0): fewer VALU ops
__device__ __forceinline__ ushort_t f2bf_fast(float f) {
    union { float f; unsigned int u; } x; x.f = f;
    return (ushort_t)((x.u + 0x8000u) >> 16);
}

__device__ __forceinline__ void async_copy16(const ushort_t* gptr, ushort_t* lptr) {
    __builtin_amdgcn_global_load_lds(
        (const __attribute__((address_space(1))) unsigned int*)gptr,
        (__attribute__((address_space(3))) unsigned int*)lptr, 16, 0, 0);
}

// ---------------- fused prep: z<4 weight transpose+cast, z>=4 q/k/v cast ----------------
__global__ __launch_bounds__(256) void prep_fused(const float* __restrict__ w0,
                                                  const float* __restrict__ w1,
                                                  const float* __restrict__ w2,
                                                  const float* __restrict__ w3,
                                                  ushort_t* __restrict__ o0,
                                                  ushort_t* __restrict__ o1,
                                                  ushort_t* __restrict__ o2,
                                                  ushort_t* __restrict__ o3,
                                                  const float* __restrict__ q,
                                                  const float* __restrict__ k,
                                                  const float* __restrict__ v,
                                                  ushort_t* __restrict__ qo,
                                                  ushort_t* __restrict__ ko,
                                                  ushort_t* __restrict__ vo) {
    const int z = blockIdx.z;
    const int tid = threadIdx.x;
    const int flat = blockIdx.x + 64 * blockIdx.y;  // 0..2047
    if (z < 4) {
        if (flat >= 1024) return;
        const int R = D_MODEL, C = D_MODEL;
        const float* in = (z == 0) ? w0 : (z == 1) ? w1 : (z == 2) ? w2 : w3;
        ushort_t* out = (z == 0) ? o0 : (z == 1) ? o1 : (z == 2) ? o2 : o3;
        __shared__ ushort_t t[32][33];
        int bc = (flat & 31) * 32, br = (flat >> 5) * 32;
        int tx = tid & 31, ty = tid >> 5;
        for (int i = ty; i < 32; i += 8)
            t[i][tx] = f2bf(in[(size_t)(br + i) * C + bc + tx]);
        __syncthreads();
        for (int i = ty; i < 32; i += 8)
            out[(size_t)(bc + i) * R + br + tx] = t[tx][i];
    } else {
        const float* s = (z == 4) ? q : (z == 5) ? k : v;
        ushort_t* d = (z == 4) ? qo : (z == 5) ? ko : vo;
        size_t i = ((size_t)flat * 256 + tid) * 8;
        float4 a = *(const float4*)(s + i);
        float4 b = *(const float4*)(s + i + 4);
        ushort_t tmp[8] = {f2bf(a.x), f2bf(a.y), f2bf(a.z), f2bf(a.w),
                           f2bf(b.x), f2bf(b.y), f2bf(b.z), f2bf(b.w)};
        *(short8*)(d + i) = *(short8*)tmp;
    }
}

// ---------------- QKV projection: 128x128 tile, both operands async, grid.z batched ----------------
// z==0: Q, scaled by QSCALE_L2E.  z==1: K.  z==2: V, written TRANSPOSED (Vt[n][m])
// with each 16-token group rotated by ((n>>2)&3)*4 so attn's LDS reads are bank-conflict-free.
__global__ __launch_bounds__(256) void gemm_qkv(const ushort_t* __restrict__ qb,
                                                const ushort_t* __restrict__ kb,
                                                const ushort_t* __restrict__ vb,
                                                const ushort_t* __restrict__ wq,
                                                const ushort_t* __restrict__ wk,
                                                const ushort_t* __restrict__ wv,
                                                ushort_t* __restrict__ Qo,
                                                ushort_t* __restrict__ Ko,
                                                ushort_t* __restrict__ VtO) {
    __shared__ ushort_t As[128 * 32];
    __shared__ ushort_t Bs[128 * 32];
    const int z = blockIdx.z;
    const ushort_t* A = (z == 0) ? qb : (z == 1) ? kb : vb;
    const ushort_t* Bt = (z == 0) ? wq : (z == 1) ? wk : wv;
    const int tid = threadIdx.x;
    const int wave = tid >> 6, lane = tid & 63;
    const int quad = lane >> 4, l16 = lane & 15;
    const int m0 = blockIdx.y * 128, n0 = blockIdx.x * 128;
    const int wm = (wave >> 1) * 64, wn = (wave & 1) * 64;
    const int K = D_MODEL, N = D_MODEL;

    f32x4 acc[4][4];
    for (int i = 0; i < 4; ++i)
        for (int j = 0; j < 4; ++j) acc[i][j] = (f32x4){0.f, 0.f, 0.f, 0.f};

    for (int kk = 0; kk < K; kk += 32) {
        __syncthreads();
        #pragma unroll
        for (int c = 0; c < 2; ++c) {
            int flat = ((wave * 2 + c) * 64 + lane) * 8;
            int r = flat >> 5, col = flat & 31;
            async_copy16(Bt + (size_t)(n0 + r) * K + kk + col, &Bs[(wave * 2 + c) * 512]);
            async_copy16(A + (size_t)(m0 + r) * K + kk + col, &As[(wave * 2 + c) * 512]);
        }
        __syncthreads();
        short8 af[4], bfr[4];
        #pragma unroll
        for (int i = 0; i < 4; ++i)
            af[i] = *(const short8*)&As[(wm + i * 16 + l16) * 32 + quad * 8];
        #pragma unroll
        for (int j = 0; j < 4; ++j)
            bfr[j] = *(const short8*)&Bs[(wn + j * 16 + l16) * 32 + quad * 8];
        #pragma unroll
        for (int i = 0; i < 4; ++i)
            #pragma unroll
            for (int j = 0; j < 4; ++j)
                acc[i][j] = __builtin_amdgcn_mfma_f32_16x16x32_bf16(af[i], bfr[j], acc[i][j], 0, 0, 0);
    }
    if (z == 2) {
        // V^T with k-rotation: within each 16-token block, quad -> (quad + (n>>2)) & 3
        #pragma unroll
        for (int i = 0; i < 4; ++i)
            #pragma unroll
            for (int j = 0; j < 4; ++j) {
                int n = n0 + wn + j * 16 + l16;
                int mBase = m0 + wm + i * 16;
                int quadR = (quad + (n >> 2)) & 3;
                ushort_t tmp[4];
                #pragma unroll
                for (int r = 0; r < 4; ++r) tmp[r] = f2bf(acc[i][j][r]);
                *(short4v*)&VtO[(size_t)n * M_TOK + mBase + quadR * 4] = *(short4v*)tmp;
            }
    } else {
        ushort_t* C = (z == 0) ? Qo : Ko;
        const float scale = (z == 0) ? QSCALE_L2E : 1.0f;
        #pragma unroll
        for (int i = 0; i < 4; ++i)
            #pragma unroll
            for (int j = 0; j < 4; ++j) {
                int n = n0 + wn + j * 16 + l16;
                #pragma unroll
                for (int r = 0; r < 4; ++r) {
                    int m = m0 + wm + i * 16 + quad * 4 + r;
                    C[(size_t)m * N + n] = f2bf(acc[i][j][r] * scale);
                }
            }
    }
}

// ---------------- FC projection, 128x64 tiles (2 blocks/CU), fused bias+residual ----------------
__global__ __launch_bounds__(256) void gemm_fc(const ushort_t* __restrict__ A,
                                               const ushort_t* __restrict__ Bt,
                                               float* __restrict__ Cf,
                                               const float* __restrict__ bias,
                                               const float* __restrict__ resid) {
    __shared__ ushort_t As[128 * 32];
    __shared__ ushort_t Bs[64 * 32];
    const int tid = threadIdx.x;
    const int wave = tid >> 6, lane = tid & 63;
    const int quad = lane >> 4, l16 = lane & 15;
    const int m0 = blockIdx.y * 128, n0 = blockIdx.x * 64;
    const int K = D_MODEL, N = D_MODEL;

    f32x4 acc[2][4];
    for (int i = 0; i < 2; ++i)
        for (int j = 0; j < 4; ++j) acc[i][j] = (f32x4){0.f, 0.f, 0.f, 0.f};

    for (int kk = 0; kk < K; kk += 32) {
        __syncthreads();
        #pragma unroll
        for (int c = 0; c < 2; ++c) {  // A: 8 chunks, wave handles 2
            int g = wave * 2 + c;
            int flat = (g * 64 + lane) * 8;
            int r = flat >> 5, col = flat & 31;
            async_copy16(A + (size_t)(m0 + r) * K + kk + col, &As[g * 512]);
        }
        {  // B: 4 chunks, wave handles 1
            int flat = (wave * 64 + lane) * 8;
            int r = flat >> 5, col = flat & 31;
            async_copy16(Bt + (size_t)(n0 + r) * K + kk + col, &Bs[wave * 512]);
        }
        __syncthreads();
        short8 af[2], bfr[4];
        #pragma unroll
        for (int i = 0; i < 2; ++i)
            af[i] = *(const short8*)&As[(wave * 32 + i * 16 + l16) * 32 + quad * 8];
        #pragma unroll
        for (int j = 0; j < 4; ++j)
            bfr[j] = *(const short8*)&Bs[(j * 16 + l16) * 32 + quad * 8];
        #pragma unroll
        for (int i = 0; i < 2; ++i)
            #pragma unroll
            for (int j = 0; j < 4; ++j)
                acc[i][j] = __builtin_amdgcn_mfma_f32_16x16x32_bf16(af[i], bfr[j], acc[i][j], 0, 0, 0);
    }
    #pragma unroll
    for (int i = 0; i < 2; ++i)
        #pragma unroll
        for (int j = 0; j < 4; ++j) {
            int n = n0 + j * 16 + l16;
            #pragma unroll
            for (int r = 0; r < 4; ++r) {
                int m = m0 + wave * 32 + i * 16 + quad * 4 + r;
                Cf[(size_t)m * N + n] = acc[i][j][r] + bias[n] + resid[(size_t)m * N + n];
            }
        }
}

// ---------------- flash attention: k-split, XCD-local heads, V dist-2 DMA ----------------
// Grid = (h, b, qt): linear block id mod 8 == h mod 8, so all 64 blocks of a head
// land on the same XCD -> the head's 512 KB K/V slice stays L2-resident (2 MB/XCD).
// Each wave owns a 16-row k-slice. Q (64 rows) + K-frags in registers.
// S^T = mfma(A=K, B=Q): C-layout == PV A-layout -> P stays in registers.
__global__ __launch_bounds__(256, 3) void attn64(const ushort_t* __restrict__ Qh,
                                                 const ushort_t* __restrict__ Kh,
                                                 const ushort_t* __restrict__ Vt,
                                                 ushort_t* __restrict__ O) {
    // loop phase: V buffers 4 waves x 3 bufs x 2KB = 24576 B
    // epilogue overlay: one fp32 64x66 region (16896 B) at offset 0; lsb after loop bufs
    __shared__ __align__(16) char smem[25600];
    const int tid = threadIdx.x;
    const int wave = tid >> 6, lane = tid & 63;
    const int quad = lane >> 4, l16 = lane & 15;
    const int h = blockIdx.x, b = blockIdx.y, qt = blockIdx.z;
    const size_t base = (size_t)b * SEQ * HD + h * 64;
    const ushort_t* Qb = Qh + base + (size_t)(qt * 64) * HD;
    const ushort_t* Kb = Kh + base;
    const ushort_t* Vb = Vt + (size_t)(h * 64) * M_TOK + (size_t)b * SEQ;

    ushort_t* Vw = (ushort_t*)smem + wave * 3072;
    float* lsb = (float*)(smem + 24576);

    // Q fragments: all 64 q-rows (B-operand), resident for the whole loop
    short8 qf[4][2];
    #pragma unroll
    for (int nt = 0; nt < 4; ++nt)
        #pragma unroll
        for (int s = 0; s < 2; ++s)
            qf[nt][s] = *(const short8*)(Qb + (size_t)(nt * 16 + l16) * HD + s * 32 + quad * 8);

    f32x4 oacc[4][4];
    #pragma unroll
    for (int nt = 0; nt < 4; ++nt)
        #pragma unroll
        for (int dt = 0; dt < 4; ++dt) oacc[nt][dt] = (f32x4){0.f, 0.f, 0.f, 0.f};
    float lsum[4] = {0.f, 0.f, 0.f, 0.f};

    // K fragment source (direct global): row = kt*64 + wave*16 + l16, col s*32 + quad*8
    const ushort_t* Kr = Kb + (size_t)(wave * 16 + l16) * HD + quad * 8;
    // V DMA source/dest
    const ushort_t* Vg = Vb + (size_t)(lane >> 1) * M_TOK + wave * 16 + (lane & 1) * 8;
    ushort_t* VLd = Vw + lane * 8;

    // prologue: kf(0) regular loads, then V(0), V(1) DMAs (order matters for vmcnt)
    short8 kf0[2], kf1[2];
    #pragma unroll
    for (int s = 0; s < 2; ++s) kf0[s] = *(const short8*)(Kr + s * 32);
    #pragma unroll
    for (int c = 0; c < 2; ++c)
        async_copy16(Vg + (size_t)c * 32 * M_TOK, VLd + c * 512);
    #pragma unroll
    for (int c = 0; c < 2; ++c)
        async_copy16(Vg + (size_t)c * 32 * M_TOK + 64, VLd + 1024 + c * 512);

    ushort_t *vb0 = Vw, *vb1 = Vw + 1024, *vb2 = Vw + 2048;
    const int rot = (l16 >> 2) & 3;  // V k-rotation (matches gemm_qkv epilogue)

    for (int kt = 0; kt < NT; ++kt) {
        if (kt == NT - 1) __builtin_amdgcn_s_waitcnt(0x0F70);  // vmcnt(0)
        else              __builtin_amdgcn_s_waitcnt(0x0F72);  // vmcnt(2)

        // prefetch K(kt+1) frags (regular loads, compiler-tracked)
        if (kt + 1 < NT) {
            #pragma unroll
            for (int s = 0; s < 2; ++s)
                kf1[s] = *(const short8*)(Kr + (size_t)(kt + 1) * 64 * HD + s * 32);
        }
        // prefetch V(kt+2) into vb2 (distance 2)
        if (kt + 2 < NT) {
            #pragma unroll
            for (int c = 0; c < 2; ++c)
                async_copy16(Vg + (size_t)c * 32 * M_TOK + (kt + 2) * 64, vb2 + lane * 8 + c * 512);
        }

        // V fragments (B-operand of 16x16x16): [d=dt*16+l16][k=quad*4+j], rotated
        short4v vf[4];
        #pragma unroll
        for (int dt = 0; dt < 4; ++dt)
            vf[dt] = *(const short4v*)&vb0[(dt * 16 + l16) * 16 + (((quad + rot) & 3) * 4)];

        // S^T = K·Q^T : lane holds S[q=nt*16+l16][k=slice + quad*4+i]
        f32x4 sacc[4];
        #pragma unroll
        for (int nt = 0; nt < 4; ++nt) sacc[nt] = (f32x4){0.f, 0.f, 0.f, 0.f};
        #pragma unroll
        for (int s = 0; s < 2; ++s)
            #pragma unroll
            for (int nt = 0; nt < 4; ++nt)
                sacc[nt] = __builtin_amdgcn_mfma_f32_16x16x32_bf16(kf0[s], qf[nt][s], sacc[nt], 0, 0, 0);

        // exp2 (single v_exp_f32), pack straight into PV A-fragments
        short4v pf[4];
        #pragma unroll
        for (int nt = 0; nt < 4; ++nt) {
            ushort_t tmp[4];
            #pragma unroll
            for (int i = 0; i < 4; ++i) {
                float pv = __builtin_amdgcn_exp2f(sacc[nt][i]);
                lsum[nt] += pv;
                tmp[i] = f2bf_fast(pv);
            }
            pf[nt] = *(short4v*)tmp;
        }
        // PV over this wave's k-slice
        #pragma unroll
        for (int nt = 0; nt < 4; ++nt)
            #pragma unroll
            for (int dt = 0; dt < 4; ++dt)
                oacc[nt][dt] = __builtin_amdgcn_mfma_f32_16x16x16bf16_1k(pf[nt], vf[dt], oacc[nt][dt], 0, 0, 0);

        kf0[0] = kf1[0]; kf0[1] = kf1[1];
        ushort_t* t = vb0; vb0 = vb1; vb1 = vb2; vb2 = t;
    }

    // lsum: sum over this wave's k-quads, publish per-wave partial
    #pragma unroll
    for (int nt = 0; nt < 4; ++nt) {
        lsum[nt] += __shfl_xor(lsum[nt], 16, 64);
        lsum[nt] += __shfl_xor(lsum[nt], 32, 64);
    }
    if (quad == 0) {
        #pragma unroll
        for (int nt = 0; nt < 4; ++nt) lsb[wave * 64 + nt * 16 + l16] = lsum[nt];
    }
    __syncthreads();  // loop LDS use done; repurpose smem as one fp32 64x66 O region

    float* R = (float*)smem;  // stride 66: exact 2-way banks for quad-strided rows
    #pragma unroll
    for (int w = 0; w < 4; ++w) {
        if (wave == w) {
            #pragma unroll
            for (int nt = 0; nt < 4; ++nt)
                #pragma unroll
                for (int dt = 0; dt < 4; ++dt)
                    #pragma unroll
                    for (int i = 0; i < 4; ++i) {
                        int idx = (nt * 16 + quad * 4 + i) * 66 + dt * 16 + l16;
                        if (w == 0) R[idx] = oacc[nt][dt][i];
                        else        R[idx] += oacc[nt][dt][i];
                    }
        }
        __syncthreads();
    }
    // final: wave w owns q-rows [w*16, w*16+16)
    float inv[4];
    #pragma unroll
    for (int i = 0; i < 4; ++i) {
        int qrow = wave * 16 + quad * 4 + i;
        float t = lsb[qrow] + lsb[64 + qrow] + lsb[128 + qrow] + lsb[192 + qrow];
        inv[i] = 1.f / t;
    }
    ushort_t* Ob = O + base + (size_t)(qt * 64) * HD;
    #pragma unroll
    for (int i = 0; i < 4; ++i) {
        int qrow = wave * 16 + quad * 4 + i;
        #pragma unroll
        for (int dt = 0; dt < 4; ++dt) {
            int d = dt * 16 + l16;
            Ob[(size_t)qrow * HD + d] = f2bf(R[qrow * 66 + d] * inv[i]);
        }
    }
}

// ---------------- in-place LayerNorm, one block per row ----------------
__global__ __launch_bounds__(256) void ln_kernel(float* __restrict__ x,
                                                 const float* __restrict__ gamma,
                                                 const float* __restrict__ beta) {
    const int D = D_MODEL;
    float* xr = x + (size_t)blockIdx.x * D;
    const int tid = threadIdx.x;
    float4 v = *(const float4*)(xr + tid * 4);
    float s = v.x + v.y + v.z + v.w;
    float s2 = v.x * v.x + v.y * v.y + v.z * v.z + v.w * v.w;
    #pragma unroll
    for (int off = 1; off < 64; off <<= 1) {
        s += __shfl_xor(s, off, 64);
        s2 += __shfl_xor(s2, off, 64);
    }
    __shared__ float ws1[4], ws2[4];
    int wave = tid >> 6, lane = tid & 63;
    if (lane == 0) { ws1[wave] = s; ws2[wave] = s2; }
    __syncthreads();
    s = ws1[0] + ws1[1] + ws1[2] + ws1[3];
    s2 = ws2[0] + ws2[1] + ws2[2] + ws2[3];
    float mean = s * (1.f / D);
    float var = s2 * (1.f / D) - mean * mean;
    float rstd = rsqrtf(var + 1e-6f);
    float4 g = *(const float4*)(gamma + tid * 4);
    float4 bt = *(const float4*)(beta + tid * 4);
    float4 o;
    o.x = (v.x - mean) * rstd * g.x + bt.x;
    o.y = (v.y - mean) * rstd * g.y + bt.y;
    o.z = (v.z - mean) * rstd * g.z + bt.z;
    o.w = (v.w - mean) * rstd * g.w + bt.w;
    *(float4*)(xr + tid * 4) = o;
}

extern "C" void kernel_launch(void* const* d_in, const int* in_sizes, int n_in,
                              void* d_out, int out_size, void* d_ws, size_t ws_size,
                              hipStream_t stream) {
    const float* q = (const float*)d_in[0];
    const float* k = (const float*)d_in[1];
    const float* v = (const float*)d_in[2];
    const float* Wq = (const float*)d_in[3];
    const float* Wk = (const float*)d_in[4];
    const float* Wv = (const float*)d_in[5];
    const float* Wfc = (const float*)d_in[6];
    const float* bfc = (const float*)d_in[7];
    const float* gamma = (const float*)d_in[8];
    const float* beta = (const float*)d_in[9];
    float* out = (float*)d_out;

    char* ws = (char*)d_ws;
    const size_t MB = 1u << 20;
    ushort_t* WqT  = (ushort_t*)(ws + 0 * MB);
    ushort_t* WkT  = (ushort_t*)(ws + 2 * MB);
    ushort_t* WvT  = (ushort_t*)(ws + 4 * MB);
    ushort_t* WfcT = (ushort_t*)(ws + 6 * MB);
    ushort_t* qb   = (ushort_t*)(ws + 8 * MB);
    ushort_t* kb   = (ushort_t*)(ws + 16 * MB);
    ushort_t* vb   = (ushort_t*)(ws + 24 * MB);
    ushort_t* Qh   = (ushort_t*)(ws + 32 * MB);
    ushort_t* Kh   = (ushort_t*)(ws + 40 * MB);
    ushort_t* Vt   = (ushort_t*)(ws + 48 * MB);
    ushort_t* Oh   = (ushort_t*)(ws + 8 * MB);  // reuse qb slot after QKV GEMM

    const int M = M_TOK, D = D_MODEL;
    prep_fused<<<dim3(64, 32, 7), 256, 0, stream>>>(
        Wq, Wk, Wv, Wfc, WqT, WkT, WvT, WfcT, q, k, v, qb, kb, vb);

    gemm_qkv<<<dim3(D / 128, M / 128, 3), 256, 0, stream>>>(qb, kb, vb, WqT, WkT, WvT, Qh, Kh, Vt);

    attn64<<<dim3(N_HEAD, BATCH, SEQ / 64), 256, 0, stream>>>(Qh, Kh, Vt, Oh);

    gemm_fc<<<dim3(D / 64, M / 128), 256, 0, stream>>>(Oh, WfcT, out, bfc, q);

    ln_kernel<<<M, 256, 0, stream>>>(out, gamma, beta);
}

// Round 7
// 241.709 us; speedup vs baseline: 1.1894x; 1.0512x over previous
//
#include <hip/hip_runtime.h>

typedef float f32x4 __attribute__((ext_vector_type(4)));
typedef short short8 __attribute__((ext_vector_type(8)));
typedef short short4v __attribute__((ext_vector_type(4)));
typedef unsigned short ushort_t;

#define D_MODEL 1024
#define N_HEAD 16
#define SEQ 2048
#define BATCH 2
#define M_TOK 4096  // B*S
#define HD 1024     // N_HEAD*D_K
#define NT 32       // SEQ/64 k-tiles
#define APANEL 131072  // 4096*32 elements per A-side k-panel
#define WPANEL 32768   // 1024*32 elements per weight k-panel
// (1/sqrt(64)) * log2(e), folded into Q-GEMM epilogue; attention uses exp2
#define QSCALE_L2E 0.1803368801111f

__device__ __forceinline__ ushort_t f2bf(float f) {
    union { float f; unsigned int u; } x; x.f = f;
    unsigned int r = x.u + 0x7fffu + ((x.u >> 16) & 1u);
    return (ushort_t)(r >> 16);
}
__device__ __forceinline__ ushort_t f2bf_fast(float f) {
    union { float f; unsigned int u; } x; x.f = f;
    return (ushort_t)((x.u + 0x8000u) >> 16);
}

__device__ __forceinline__ void async_copy16(const ushort_t* gptr, ushort_t* lptr) {
    __builtin_amdgcn_global_load_lds(
        (const __attribute__((address_space(1))) unsigned int*)gptr,
        (__attribute__((address_space(3))) unsigned int*)lptr, 16, 0, 0);
}

// ---- fused prep: z<4 weight transpose+cast -> panel layout [k/32][1024][32];
//      z>=4 q/k/v cast -> panel layout [k/32][4096][32] ----
__global__ __launch_bounds__(256) void prep_fused(const float* __restrict__ w0,
                                                  const float* __restrict__ w1,
                                                  const float* __restrict__ w2,
                                                  const float* __restrict__ w3,
                                                  ushort_t* __restrict__ o0,
                                                  ushort_t* __restrict__ o1,
                                                  ushort_t* __restrict__ o2,
                                                  ushort_t* __restrict__ o3,
                                                  const float* __restrict__ q,
                                                  const float* __restrict__ k,
                                                  const float* __restrict__ v,
                                                  ushort_t* __restrict__ qo,
                                                  ushort_t* __restrict__ ko,
                                                  ushort_t* __restrict__ vo) {
    const int z = blockIdx.z;
    const int tid = threadIdx.x;
    const int flat = blockIdx.x + 64 * blockIdx.y;  // 0..2047
    if (z < 4) {
        if (flat >= 1024) return;
        const int C = D_MODEL;
        const float* in = (z == 0) ? w0 : (z == 1) ? w1 : (z == 2) ? w2 : w3;
        ushort_t* out = (z == 0) ? o0 : (z == 1) ? o1 : (z == 2) ? o2 : o3;
        __shared__ ushort_t t[32][33];
        int bc = (flat & 31) * 32, br = (flat >> 5) * 32;  // br = k-block, bc = n-block
        int tx = tid & 31, ty = tid >> 5;
        for (int i = ty; i < 32; i += 8)
            t[i][tx] = f2bf(in[(size_t)(br + i) * C + bc + tx]);
        __syncthreads();
        // element (n = bc+i, k = br+tx) -> panel (br>>5), addr n*32 + tx
        size_t pbase = (size_t)(br >> 5) * WPANEL;
        for (int i = ty; i < 32; i += 8)
            out[pbase + (size_t)(bc + i) * 32 + tx] = t[tx][i];
    } else {
        const float* s = (z == 4) ? q : (z == 5) ? k : v;
        ushort_t* d = (z == 4) ? qo : (z == 5) ? ko : vo;
        size_t i = ((size_t)flat * 256 + tid) * 8;
        int m = (int)(i >> 10), k0 = (int)(i & 1023);
        float4 a = *(const float4*)(s + i);
        float4 b = *(const float4*)(s + i + 4);
        ushort_t tmp[8] = {f2bf(a.x), f2bf(a.y), f2bf(a.z), f2bf(a.w),
                           f2bf(b.x), f2bf(b.y), f2bf(b.z), f2bf(b.w)};
        *(short8*)(d + (size_t)(k0 >> 5) * APANEL + (size_t)m * 32 + (k0 & 31)) = *(short8*)tmp;
    }
}

// ---- QKV projection: 128x128 tile, BK=64 (2 panels/iter), grid.z batched ----
// z==0: Q scaled by QSCALE_L2E (row-major out). z==1: K (row-major out).
// z==2: V -> blocked V4[h][b][kt][w][d][16k] with k-rotation, ready for attn DMA.
__global__ __launch_bounds__(256) void gemm_qkv(const ushort_t* __restrict__ qb,
                                                const ushort_t* __restrict__ kb,
                                                const ushort_t* __restrict__ vb,
                                                const ushort_t* __restrict__ wq,
                                                const ushort_t* __restrict__ wk,
                                                const ushort_t* __restrict__ wv,
                                                ushort_t* __restrict__ Qo,
                                                ushort_t* __restrict__ Ko,
                                                ushort_t* __restrict__ V4) {
    __shared__ ushort_t As[2][128 * 32];
    __shared__ ushort_t Bs[2][128 * 32];
    const int z = blockIdx.z;
    const ushort_t* A = (z == 0) ? qb : (z == 1) ? kb : vb;
    const ushort_t* Bt = (z == 0) ? wq : (z == 1) ? wk : wv;
    const int tid = threadIdx.x;
    const int wave = tid >> 6, lane = tid & 63;
    const int quad = lane >> 4, l16 = lane & 15;
    const int m0 = blockIdx.y * 128, n0 = blockIdx.x * 128;
    const int wm = (wave >> 1) * 64, wn = (wave & 1) * 64;
    const int N = D_MODEL;

    f32x4 acc[4][4];
    for (int i = 0; i < 4; ++i)
        for (int j = 0; j < 4; ++j) acc[i][j] = (f32x4){0.f, 0.f, 0.f, 0.f};

    for (int it = 0; it < 16; ++it) {
        __syncthreads();
        const ushort_t* Ap = A + (size_t)(it * 2) * APANEL + (size_t)m0 * 32;
        const ushort_t* Bp = Bt + (size_t)(it * 2) * WPANEL + (size_t)n0 * 32;
        #pragma unroll
        for (int hf = 0; hf < 2; ++hf) {
            #pragma unroll
            for (int c = 0; c < 2; ++c) {
                int off = (wave * 2 + c) * 512;
                async_copy16(Ap + hf * APANEL + off + lane * 8, &As[hf][off] + lane * 8);
                async_copy16(Bp + hf * WPANEL + off + lane * 8, &Bs[hf][off] + lane * 8);
            }
        }
        __syncthreads();
        short8 af[4][2], bfr[4][2];
        #pragma unroll
        for (int i = 0; i < 4; ++i)
            #pragma unroll
            for (int sk = 0; sk < 2; ++sk)
                af[i][sk] = *(const short8*)&As[sk][(wm + i * 16 + l16) * 32 + quad * 8];
        #pragma unroll
        for (int j = 0; j < 4; ++j)
            #pragma unroll
            for (int sk = 0; sk < 2; ++sk)
                bfr[j][sk] = *(const short8*)&Bs[sk][(wn + j * 16 + l16) * 32 + quad * 8];
        #pragma unroll
        for (int sk = 0; sk < 2; ++sk)
            #pragma unroll
            for (int i = 0; i < 4; ++i)
                #pragma unroll
                for (int j = 0; j < 4; ++j)
                    acc[i][j] = __builtin_amdgcn_mfma_f32_16x16x32_bf16(af[i][sk], bfr[j][sk], acc[i][j], 0, 0, 0);
    }
    if (z == 2) {
        // V4 blocked layout: tile64 = 64-token group; w-subtile = i; token slot rotated
        const int tile64 = m0 + wm;
        const int b2 = tile64 >> 11;            // /SEQ
        const int kt = (tile64 & 2047) >> 6;
        #pragma unroll
        for (int i = 0; i < 4; ++i)
            #pragma unroll
            for (int j = 0; j < 4; ++j) {
                int n = n0 + wn + j * 16 + l16;
                int h2 = n >> 6, d = n & 63;
                int quadR = (quad + ((n >> 2) & 3)) & 3;
                ushort_t tmp[4];
                #pragma unroll
                for (int r = 0; r < 4; ++r) tmp[r] = f2bf(acc[i][j][r]);
                size_t dst = ((((size_t)(h2 * 2 + b2) * NT + kt) * 4 + i) << 10) + d * 16 + quadR * 4;
                *(short4v*)&V4[dst] = *(short4v*)tmp;
            }
    } else {
        ushort_t* C = (z == 0) ? Qo : Ko;
        const float scale = (z == 0) ? QSCALE_L2E : 1.0f;
        #pragma unroll
        for (int i = 0; i < 4; ++i)
            #pragma unroll
            for (int j = 0; j < 4; ++j) {
                int n = n0 + wn + j * 16 + l16;
                #pragma unroll
                for (int r = 0; r < 4; ++r) {
                    int m = m0 + wm + i * 16 + quad * 4 + r;
                    C[(size_t)m * N + n] = f2bf(acc[i][j][r] * scale);
                }
            }
    }
}

// ---- FC projection: 128x64 tiles, BK=64 panels, fused bias + residual, fp32 out ----
__global__ __launch_bounds__(256) void gemm_fc(const ushort_t* __restrict__ A,
                                               const ushort_t* __restrict__ Bt,
                                               float* __restrict__ Cf,
                                               const float* __restrict__ bias,
                                               const float* __restrict__ resid) {
    __shared__ ushort_t As[2][128 * 32];
    __shared__ ushort_t Bs[2][64 * 32];
    const int tid = threadIdx.x;
    const int wave = tid >> 6, lane = tid & 63;
    const int quad = lane >> 4, l16 = lane & 15;
    const int m0 = blockIdx.y * 128, n0 = blockIdx.x * 64;
    const int N = D_MODEL;

    f32x4 acc[2][4];
    for (int i = 0; i < 2; ++i)
        for (int j = 0; j < 4; ++j) acc[i][j] = (f32x4){0.f, 0.f, 0.f, 0.f};

    for (int it = 0; it < 16; ++it) {
        __syncthreads();
        const ushort_t* Ap = A + (size_t)(it * 2) * APANEL + (size_t)m0 * 32;
        const ushort_t* Bp = Bt + (size_t)(it * 2) * WPANEL + (size_t)n0 * 32;
        #pragma unroll
        for (int c = 0; c < 4; ++c) {  // A: 16 instrs, wave does 4
            int g = wave * 4 + c;
            int sk = g >> 3, off = (g & 7) * 512;
            async_copy16(Ap + sk * APANEL + off + lane * 8, &As[sk][off] + lane * 8);
        }
        #pragma unroll
        for (int c = 0; c < 2; ++c) {  // B: 8 instrs, wave does 2
            int g = wave * 2 + c;
            int sk = g >> 2, off = (g & 3) * 512;
            async_copy16(Bp + sk * WPANEL + off + lane * 8, &Bs[sk][off] + lane * 8);
        }
        __syncthreads();
        short8 af[2][2], bfr[4][2];
        #pragma unroll
        for (int i = 0; i < 2; ++i)
            #pragma unroll
            for (int sk = 0; sk < 2; ++sk)
                af[i][sk] = *(const short8*)&As[sk][(wave * 32 + i * 16 + l16) * 32 + quad * 8];
        #pragma unroll
        for (int j = 0; j < 4; ++j)
            #pragma unroll
            for (int sk = 0; sk < 2; ++sk)
                bfr[j][sk] = *(const short8*)&Bs[sk][(j * 16 + l16) * 32 + quad * 8];
        #pragma unroll
        for (int sk = 0; sk < 2; ++sk)
            #pragma unroll
            for (int i = 0; i < 2; ++i)
                #pragma unroll
                for (int j = 0; j < 4; ++j)
                    acc[i][j] = __builtin_amdgcn_mfma_f32_16x16x32_bf16(af[i][sk], bfr[j][sk], acc[i][j], 0, 0, 0);
    }
    #pragma unroll
    for (int i = 0; i < 2; ++i)
        #pragma unroll
        for (int j = 0; j < 4; ++j) {
            int n = n0 + j * 16 + l16;
            #pragma unroll
            for (int r = 0; r < 4; ++r) {
                int m = m0 + wave * 32 + i * 16 + quad * 4 + r;
                Cf[(size_t)m * N + n] = acc[i][j][r] + bias[n] + resid[(size_t)m * N + n];
            }
        }
}

// ---- flash attention: k-split, XCD-local heads, blocked-V DMA (contiguous 2KB/slice) ----
// Grid = (h, b, qt): block id mod 8 == h mod 8 -> head's K/V stays in one XCD's L2.
// Wave owns a 16-row k-slice; Q (64 rows) + K-frags in registers.
// S^T = mfma(A=K, B=Q): C-layout == PV A-layout -> P stays in registers.
// O written in panel layout [k/32][M_TOK][32] for gemm_fc.
__global__ __launch_bounds__(256, 3) void attn64(const ushort_t* __restrict__ Qh,
                                                 const ushort_t* __restrict__ Kh,
                                                 const ushort_t* __restrict__ V4,
                                                 ushort_t* __restrict__ O) {
    // loop: V buffers 4 waves x 3 bufs x 2KB = 24576 B; epilogue overlay 64x66 fp32 + lsb
    __shared__ __align__(16) char smem[25600];
    const int tid = threadIdx.x;
    const int wave = tid >> 6, lane = tid & 63;
    const int quad = lane >> 4, l16 = lane & 15;
    const int h = blockIdx.x, b = blockIdx.y, qt = blockIdx.z;
    const size_t base = (size_t)b * SEQ * HD + h * 64;
    const ushort_t* Qb = Qh + base + (size_t)(qt * 64) * HD;
    const ushort_t* Kb = Kh + base;
    // wave's V stream: V4[h][b][kt][wave][1024], kt stride 4096 el
    const ushort_t* Vg = V4 + (((size_t)(h * 2 + b) * NT * 4) + wave) * 1024 + lane * 8;

    ushort_t* Vw = (ushort_t*)smem + wave * 3072;
    float* lsb = (float*)(smem + 24576);

    short8 qf[4][2];
    #pragma unroll
    for (int nt = 0; nt < 4; ++nt)
        #pragma unroll
        for (int s = 0; s < 2; ++s)
            qf[nt][s] = *(const short8*)(Qb + (size_t)(nt * 16 + l16) * HD + s * 32 + quad * 8);

    f32x4 oacc[4][4];
    #pragma unroll
    for (int nt = 0; nt < 4; ++nt)
        #pragma unroll
        for (int dt = 0; dt < 4; ++dt) oacc[nt][dt] = (f32x4){0.f, 0.f, 0.f, 0.f};
    float lsum[4] = {0.f, 0.f, 0.f, 0.f};

    const ushort_t* Kr = Kb + (size_t)(wave * 16 + l16) * HD + quad * 8;
    ushort_t* VLd = Vw + lane * 8;

    // prologue: kf(0) regular loads, then V(0), V(1) DMAs
    short8 kf0[2], kf1[2];
    #pragma unroll
    for (int s = 0; s < 2; ++s) kf0[s] = *(const short8*)(Kr + s * 32);
    #pragma unroll
    for (int c = 0; c < 2; ++c) async_copy16(Vg + c * 512, VLd + c * 512);
    #pragma unroll
    for (int c = 0; c < 2; ++c) async_copy16(Vg + 4096 + c * 512, VLd + 1024 + c * 512);

    ushort_t *vb0 = Vw, *vb1 = Vw + 1024, *vb2 = Vw + 2048;
    const int rot = (l16 >> 2) & 3;

    for (int kt = 0; kt < NT; ++kt) {
        if (kt == NT - 1) __builtin_amdgcn_s_waitcnt(0x0F70);  // vmcnt(0)
        else              __builtin_amdgcn_s_waitcnt(0x0F72);  // vmcnt(2)

        if (kt + 1 < NT) {
            #pragma unroll
            for (int s = 0; s < 2; ++s)
                kf1[s] = *(const short8*)(Kr + (size_t)(kt + 1) * 64 * HD + s * 32);
        }
        if (kt + 2 < NT) {
            #pragma unroll
            for (int c = 0; c < 2; ++c)
                async_copy16(Vg + (size_t)(kt + 2) * 4096 + c * 512, vb2 + lane * 8 + c * 512);
        }

        short4v vf[4];
        #pragma unroll
        for (int dt = 0; dt < 4; ++dt)
            vf[dt] = *(const short4v*)&vb0[(dt * 16 + l16) * 16 + (((quad + rot) & 3) * 4)];

        f32x4 sacc[4];
        #pragma unroll
        for (int nt = 0; nt < 4; ++nt) sacc[nt] = (f32x4){0.f, 0.f, 0.f, 0.f};
        #pragma unroll
        for (int s = 0; s < 2; ++s)
            #pragma unroll
            for (int nt = 0; nt < 4; ++nt)
                sacc[nt] = __builtin_amdgcn_mfma_f32_16x16x32_bf16(kf0[s], qf[nt][s], sacc[nt], 0, 0, 0);

        short4v pf[4];
        #pragma unroll
        for (int nt = 0; nt < 4; ++nt) {
            ushort_t tmp[4];
            #pragma unroll
            for (int i = 0; i < 4; ++i) {
                float pv = __builtin_amdgcn_exp2f(sacc[nt][i]);
                lsum[nt] += pv;
                tmp[i] = f2bf_fast(pv);
            }
            pf[nt] = *(short4v*)tmp;
        }
        #pragma unroll
        for (int nt = 0; nt < 4; ++nt)
            #pragma unroll
            for (int dt = 0; dt < 4; ++dt)
                oacc[nt][dt] = __builtin_amdgcn_mfma_f32_16x16x16bf16_1k(pf[nt], vf[dt], oacc[nt][dt], 0, 0, 0);

        kf0[0] = kf1[0]; kf0[1] = kf1[1];
        ushort_t* t = vb0; vb0 = vb1; vb1 = vb2; vb2 = t;
    }

    #pragma unroll
    for (int nt = 0; nt < 4; ++nt) {
        lsum[nt] += __shfl_xor(lsum[nt], 16, 64);
        lsum[nt] += __shfl_xor(lsum[nt], 32, 64);
    }
    if (quad == 0) {
        #pragma unroll
        for (int nt = 0; nt < 4; ++nt) lsb[wave * 64 + nt * 16 + l16] = lsum[nt];
    }
    __syncthreads();

    float* R = (float*)smem;  // 64x66 fp32
    #pragma unroll
    for (int w = 0; w < 4; ++w) {
        if (wave == w) {
            #pragma unroll
            for (int nt = 0; nt < 4; ++nt)
                #pragma unroll
                for (int dt = 0; dt < 4; ++dt)
                    #pragma unroll
                    for (int i = 0; i < 4; ++i) {
                        int idx = (nt * 16 + quad * 4 + i) * 66 + dt * 16 + l16;
                        if (w == 0) R[idx] = oacc[nt][dt][i];
                        else        R[idx] += oacc[nt][dt][i];
                    }
        }
        __syncthreads();
    }
    float inv[4];
    #pragma unroll
    for (int i = 0; i < 4; ++i) {
        int qrow = wave * 16 + quad * 4 + i;
        float t = lsb[qrow] + lsb[64 + qrow] + lsb[128 + qrow] + lsb[192 + qrow];
        inv[i] = 1.f / t;
    }
    // O in panel layout: k = h*64 + dt*16 + l16 -> panel h*2 + (dt>>1)
    #pragma unroll
    for (int i = 0; i < 4; ++i) {
        int qrow = wave * 16 + quad * 4 + i;
        size_t tok = (size_t)b * SEQ + qt * 64 + qrow;
        #pragma unroll
        for (int dt = 0; dt < 4; ++dt) {
            int d = dt * 16 + l16;
            size_t dst = (size_t)(h * 2 + (dt >> 1)) * APANEL + tok * 32 + (dt & 1) * 16 + l16;
            O[dst] = f2bf(R[qrow * 66 + d] * inv[i]);
        }
    }
}

// ---------------- in-place LayerNorm, one block per row ----------------
__global__ __launch_bounds__(256) void ln_kernel(float* __restrict__ x,
                                                 const float* __restrict__ gamma,
                                                 const float* __restrict__ beta) {
    const int D = D_MODEL;
    float* xr = x + (size_t)blockIdx.x * D;
    const int tid = threadIdx.x;
    float4 v = *(const float4*)(xr + tid * 4);
    float s = v.x + v.y + v.z + v.w;
    float s2 = v.x * v.x + v.y * v.y + v.z * v.z + v.w * v.w;
    #pragma unroll
    for (int off = 1; off < 64; off <<= 1) {
        s += __shfl_xor(s, off, 64);
        s2 += __shfl_xor(s2, off, 64);
    }
    __shared__ float ws1[4], ws2[4];
    int wave = tid >> 6, lane = tid & 63;
    if (lane == 0) { ws1[wave] = s; ws2[wave] = s2; }
    __syncthreads();
    s = ws1[0] + ws1[1] + ws1[2] + ws1[3];
    s2 = ws2[0] + ws2[1] + ws2[2] + ws2[3];
    float mean = s * (1.f / D);
    float var = s2 * (1.f / D) - mean * mean;
    float rstd = rsqrtf(var + 1e-6f);
    float4 g = *(const float4*)(gamma + tid * 4);
    float4 bt = *(const float4*)(beta + tid * 4);
    float4 o;
    o.x = (v.x - mean) * rstd * g.x + bt.x;
    o.y = (v.y - mean) * rstd * g.y + bt.y;
    o.z = (v.z - mean) * rstd * g.z + bt.z;
    o.w = (v.w - mean) * rstd * g.w + bt.w;
    *(float4*)(xr + tid * 4) = o;
}

extern "C" void kernel_launch(void* const* d_in, const int* in_sizes, int n_in,
                              void* d_out, int out_size, void* d_ws, size_t ws_size,
                              hipStream_t stream) {
    const float* q = (const float*)d_in[0];
    const float* k = (const float*)d_in[1];
    const float* v = (const float*)d_in[2];
    const float* Wq = (const float*)d_in[3];
    const float* Wk = (const float*)d_in[4];
    const float* Wv = (const float*)d_in[5];
    const float* Wfc = (const float*)d_in[6];
    const float* bfc = (const float*)d_in[7];
    const float* gamma = (const float*)d_in[8];
    const float* beta = (const float*)d_in[9];
    float* out = (float*)d_out;

    char* ws = (char*)d_ws;
    const size_t MB = 1u << 20;
    ushort_t* WqT  = (ushort_t*)(ws + 0 * MB);
    ushort_t* WkT  = (ushort_t*)(ws + 2 * MB);
    ushort_t* WvT  = (ushort_t*)(ws + 4 * MB);
    ushort_t* WfcT = (ushort_t*)(ws + 6 * MB);
    ushort_t* qb   = (ushort_t*)(ws + 8 * MB);
    ushort_t* kb   = (ushort_t*)(ws + 16 * MB);
    ushort_t* vb   = (ushort_t*)(ws + 24 * MB);
    ushort_t* Qh   = (ushort_t*)(ws + 32 * MB);
    ushort_t* Kh   = (ushort_t*)(ws + 40 * MB);
    ushort_t* Vt   = (ushort_t*)(ws + 48 * MB);
    ushort_t* Oh   = (ushort_t*)(ws + 8 * MB);  // reuse qb slot after QKV GEMM

    const int M = M_TOK, D = D_MODEL;
    prep_fused<<<dim3(64, 32, 7), 256, 0, stream>>>(
        Wq, Wk, Wv, Wfc, WqT, WkT, WvT, WfcT, q, k, v, qb, kb, vb);

    gemm_qkv<<<dim3(D / 128, M / 128, 3), 256, 0, stream>>>(qb, kb, vb, WqT, WkT, WvT, Qh, Kh, Vt);

    attn64<<<dim3(N_HEAD, BATCH, SEQ / 64), 256, 0, stream>>>(Qh, Kh, Vt, Oh);

    gemm_fc<<<dim3(D / 64, M / 128), 256, 0, stream>>>(Oh, WfcT, out, bfc, q);

    ln_kernel<<<M, 256, 0, stream>>>(out, gamma, beta);
}